// Round 2
// baseline (395.852 us; speedup 1.0000x reference)
//
#include <hip/hip_runtime.h>
#include <math.h>

#define TLEN 2048
#define T2   4096
#define H2   2048
#define NBLK 512
#define EPS32 1.1920928955078125e-07

// agent-scope atomic load: always reads the coherent copy
__device__ __forceinline__ double ld_acc(const double* p){
  return __hip_atomic_load(p, __ATOMIC_RELAXED, __HIP_MEMORY_SCOPE_AGENT);
}

// ---- software grid barrier (512 co-resident blocks; distinct counter per use,
//      zeroed host-side via hipMemsetAsync each launch). Release/acquire fences
//      give cross-XCD visibility for plain stores (G16). Bounded spin: on any
//      co-residency surprise we fail loud instead of hanging the queue. ----
__device__ __forceinline__ void gbar(unsigned* bar){
  __syncthreads();
  if (threadIdx.x == 0){
    __threadfence();                          // release: wb dirty L2 -> coherent point
    __hip_atomic_fetch_add(bar, 1u, __ATOMIC_RELAXED, __HIP_MEMORY_SCOPE_AGENT);
    unsigned spins = 0;
    while (__hip_atomic_load(bar, __ATOMIC_RELAXED, __HIP_MEMORY_SCOPE_AGENT) < NBLK){
      if (++spins > (1u << 22)) break;        // safety valve
      __builtin_amdgcn_s_sleep(2);
    }
    __threadfence();                          // acquire: invalidate stale L2 lines
  }
  __syncthreads();
}

// ---- 6-stage Stockham radix-4 FFT over 4096 pts in LDS; result lands in bufA.
//      sgn=+1 forward, -1 inverse. Caller must __syncthreads() after filling bufA.
__device__ __forceinline__ void fft_r4(float2* bufA, float2* bufB,
                                       const float2* __restrict__ tw, float sgn){
  float2* src = bufA; float2* dst = bufB;
  const int tid = threadIdx.x;
  #pragma unroll
  for (int st = 0; st < 6; ++st){
    const int sh = 2 * st;
    const int L = 1 << sh;
    const int Lmask = L - 1;
    #pragma unroll
    for (int bf = 0; bf < 4; ++bf){
      int idx = tid + (bf << 8);            // 0..1023
      int q  = idx & Lmask;
      int tb = idx ^ q;                     // p*L  (<= 1023)
      float2 a = src[idx];
      float2 b = src[idx + 1024];
      float2 c = src[idx + 2048];
      float2 d = src[idx + 3072];
      float2 w1 = tw[tb];
      float2 w2 = tw[2 * tb];
      float2 w3 = tw[3 * tb];
      float w1y = sgn * w1.y, w2y = sgn * w2.y, w3y = sgn * w3.y;
      float t0x = a.x + c.x, t0y = a.y + c.y;
      float t1x = a.x - c.x, t1y = a.y - c.y;
      float t2x = b.x + d.x, t2y = b.y + d.y;
      // fwd: -i*(b-d) = (y,-x); inv: +i*(b-d) = (-y,x)
      float t3x = sgn * (b.y - d.y);
      float t3y = -sgn * (b.x - d.x);
      float y0x = t0x + t2x, y0y = t0y + t2y;
      float y1x = t1x + t3x, y1y = t1y + t3y;
      float y2x = t0x - t2x, y2y = t0y - t2y;
      float y3x = t1x - t3x, y3y = t1y - t3y;
      int ob = q + (tb << 2);               // q + 4*p*L
      dst[ob]         = make_float2(y0x, y0y);
      dst[ob + L]     = make_float2(y1x * w1.x - y1y * w1y, y1x * w1y + y1y * w1.x);
      dst[ob + 2 * L] = make_float2(y2x * w2.x - y2y * w2y, y2x * w2y + y2y * w2.x);
      dst[ob + 3 * L] = make_float2(y3x * w3.x - y3y * w3y, y3x * w3y + y3y * w3.x);
    }
    __syncthreads();
    float2* t = src; src = dst; dst = t;
  }
}

// ---- block-reduce 9 doubles -> atomicAdd (device scope) into accs[0..8] ----
__device__ __forceinline__ void reduce9(double* acc, double* red, double* accs){
  const int tid = threadIdx.x, wave = tid >> 6, lane = tid & 63;
  #pragma unroll
  for (int i = 0; i < 9; ++i){
    double v = acc[i];
    for (int off = 32; off; off >>= 1) v += __shfl_down(v, off);
    if (lane == 0) red[i * 4 + wave] = v;
  }
  __syncthreads();
  if (tid < 9)
    atomicAdd(&accs[tid], red[tid*4+0] + red[tid*4+1] + red[tid*4+2] + red[tid*4+3]);
}

// ---- per-bin 4-mode Gauss-Seidel chain, with stats ----
__device__ __forceinline__ void vmd_bin(float Fx, float Fy, float fj,
                                        const float* om, float* ux, float* uy,
                                        double* aFP, double* aP, double& aD){
  float sx = ux[0] + ux[1] + ux[2] + ux[3];
  float sy = uy[0] + uy[1] + uy[2] + uy[3];
  #pragma unroll
  for (int k = 0; k < 4; ++k){
    float ox = sx - ux[k], oy = sy - uy[k];
    float d = fj - om[k];
    float den = 1.0f + 2000.0f * d * d;
    float nx = (Fx - ox) / den, ny = (Fy - oy) / den;
    float pw = nx * nx + ny * ny;
    aFP[k] += (double)(fj * pw);
    aP[k]  += (double)pw;
    float ddx = nx - ux[k], ddy = ny - uy[k];
    aD += (double)(ddx * ddx + ddy * ddy);
    ux[k] = nx; uy[k] = ny;
    sx = ox + nx; sy = oy + ny;
  }
}

// ==== whole pipeline, one normally-launched kernel with software grid barriers ====
// 512 blocks x 256 thr; 64 KiB static LDS forces exactly 2 blocks/CU -> all resident.
__global__ void __launch_bounds__(256, 2)
k_fused(const float* __restrict__ x, float* __restrict__ xr,
        float2* __restrict__ tw, unsigned* __restrict__ bar,
        double* __restrict__ accs, float* __restrict__ xl_s,
        float* __restrict__ xh, float* __restrict__ xl){
  __shared__ float2 bufA[T2];
  __shared__ float2 bufB[T2];
  const int blk = blockIdx.x, tid = threadIdx.x;

  // ---- phase A: transpose x -> xr (blocks 0..255); twiddles (256..267) ----
  if (blk < 256){
    float (*tile)[65] = reinterpret_cast<float(*)[65]>(bufA);
    const int b = blk >> 5, t0 = (blk & 31) << 6, lo = tid & 63, r0 = tid >> 6;
    #pragma unroll
    for (int pass = 0; pass < 16; ++pass){
      int tt = r0 + (pass << 2);
      tile[tt][lo] = x[((size_t)(b * TLEN + t0 + tt)) * 64 + lo];
    }
    __syncthreads();
    #pragma unroll
    for (int pass = 0; pass < 16; ++pass){
      int c2 = r0 + (pass << 2);
      xr[((size_t)(b * 64 + c2)) * TLEN + t0 + lo] = tile[lo][c2];
    }
  } else if (blk < 268){
    int p = ((blk - 256) << 8) + tid;          // 0..3071 (radix-4 needs 3*tb <= 3069)
    double a = -6.283185307179586 * (double)p / 4096.0;
    tw[p] = make_float2((float)cos(a), (float)sin(a));
  }
  gbar(bar + 0);

  // ---- phase B: mirror-extend + forward FFT; F and u live in registers ----
  float Fx[8], Fy[8], ux[8][4], uy[8][4];
  {
    const float* f = xr + (size_t)blk * TLEN;
    #pragma unroll
    for (int pp = 0; pp < 16; ++pp){
      int i = tid + (pp << 8);
      int s = (i < 1024) ? (1023 - i) : ((i < 3072) ? (i - 1024) : (5119 - i));
      bufA[i] = make_float2(f[s], 0.0f);
    }
    __syncthreads();
    fft_r4(bufA, bufB, tw, 1.0f);              // 6 stages -> result back in bufA
    #pragma unroll
    for (int pp = 0; pp < 8; ++pp){
      float2 v = bufA[tid + (pp << 8)];
      Fx[pp] = v.x; Fy[pp] = v.y;
    }
  }
  // iter 1 (u starts at 0)
  {
    const float om1[4] = {0.0f, 0.125f, 0.25f, 0.375f};
    double aFP[4] = {0,0,0,0}, aP[4] = {0,0,0,0}, aD = 0.0;
    #pragma unroll
    for (int pp = 0; pp < 8; ++pp){
      #pragma unroll
      for (int k = 0; k < 4; ++k){ ux[pp][k] = 0.0f; uy[pp][k] = 0.0f; }
      float fj = (float)(tid + (pp << 8)) * (1.0f / 4096.0f);
      vmd_bin(Fx[pp], Fy[pp], fj, om1, ux[pp], uy[pp], aFP, aP, aD);
    }
    double acc[9] = {aFP[0],aFP[1],aFP[2],aFP[3],aP[0],aP[1],aP[2],aP[3],aD};
    reduce9(acc, (double*)bufB, accs);
  }
  gbar(bar + 1);

  // ---- phase C: iters 2..4, state stays in registers ----
  bool active = true;
  double* slot = accs;                         // stats of last completed iter
  #pragma unroll 1
  for (int it = 0; it < 3; ++it){
    float om[4] = {0.f, 0.f, 0.f, 0.f};
    if (active){
      if (ld_acc(slot + 8) * (1.0 / 4096.0) + EPS32 > 5e-5){
        #pragma unroll
        for (int k = 0; k < 4; ++k)
          om[k] = (float)(ld_acc(slot + k) / ld_acc(slot + 4 + k));
      } else active = false;
    }
    if (active){
      double aFP[4] = {0,0,0,0}, aP[4] = {0,0,0,0}, aD = 0.0;
      #pragma unroll
      for (int pp = 0; pp < 8; ++pp){
        float fj = (float)(tid + (pp << 8)) * (1.0f / 4096.0f);
        vmd_bin(Fx[pp], Fy[pp], fj, om, ux[pp], uy[pp], aFP, aP, aD);
      }
      double acc[9] = {aFP[0],aFP[1],aFP[2],aFP[3],aP[0],aP[1],aP[2],aP[3],aD};
      reduce9(acc, (double*)bufB, slot + 9);
    }
    gbar(bar + 2 + it);
    slot += 9;
  }

  // ---- phase D: guarded iter-5 mode-0 update + Hermitian build + inverse FFT ----
  {
    bool act = active;
    float om0 = 0.0f;
    if (act){
      if (ld_acc(slot + 8) * (1.0 / 4096.0) + EPS32 > 5e-5)
        om0 = (float)(ld_acc(slot) / ld_acc(slot + 4));
      else act = false;
    }
    #pragma unroll
    for (int pp = 0; pp < 8; ++pp){
      int j = tid + (pp << 8);
      float vx, vy;
      if (act){                 // u0^(5) = (F - sum_{k>0} u_k^(4)) / den
        float sx = ux[pp][1] + ux[pp][2] + ux[pp][3];
        float sy = uy[pp][1] + uy[pp][2] + uy[pp][3];
        float fj = (float)j * (1.0f / 4096.0f);
        float dd = fj - om0;
        float den = 1.0f + 2000.0f * dd * dd;
        vx = (Fx[pp] - sx) / den; vy = (Fy[pp] - sy) / den;
      } else {
        vx = ux[pp][0]; vy = uy[pp][0];
      }
      if (j == 0){
        bufA[0] = make_float2(vx, -vy);               // S[0] = conj(U[0])
      } else {
        bufA[j]      = make_float2(vx, vy);           // S[j] = U[j]
        bufA[T2 - j] = make_float2(vx, -vy);          // S[4096-j] = conj(U[j])
      }
      if (j == H2 - 1) bufA[H2] = make_float2(vx, -vy); // S[2048] = conj(U[2047])
    }
    __syncthreads();
    fft_r4(bufA, bufB, tw, -1.0f);
    const float scale = 1.0f / (float)T2;
    #pragma unroll
    for (int pp = 0; pp < 8; ++pp){
      int t = tid + (pp << 8);
      xl_s[(size_t)blk * TLEN + t] = bufA[1024 + t].x * scale;
    }
  }
  gbar(bar + 5);

  // ---- phase E: transpose back + x_h = x - x_l (blocks 0..255) ----
  if (blk < 256){
    float (*tile)[65] = reinterpret_cast<float(*)[65]>(bufA);
    const int b = blk >> 5, t0 = (blk & 31) << 6, lo = tid & 63, r0 = tid >> 6;
    #pragma unroll
    for (int pass = 0; pass < 16; ++pass){
      int c2 = r0 + (pass << 2);
      tile[c2][lo] = xl_s[((size_t)(b * 64 + c2)) * TLEN + t0 + lo];
    }
    __syncthreads();
    #pragma unroll
    for (int pass = 0; pass < 16; ++pass){
      int tt = r0 + (pass << 2);
      size_t oi = ((size_t)(b * TLEN + t0 + tt)) * 64 + lo;
      float xlv = tile[lo][tt];
      float xv  = x[oi];
      xh[oi] = xv - xlv;
      xl[oi] = xlv;
    }
  }
}

extern "C" void kernel_launch(void* const* d_in, const int* in_sizes, int n_in,
                              void* d_out, int out_size, void* d_ws, size_t ws_size,
                              hipStream_t stream){
  const float* x = (const float*)d_in[0];
  float* out_xh = (float*)d_out;
  float* out_xl = out_xh + (size_t)8 * TLEN * 64;

  char* ws = (char*)d_ws;
  float*  xr   = (float*)ws;                                // 4 MiB
  float*  xl_s = (float*)(ws + ((size_t)4 << 20));          // 4 MiB
  float2* tw   = (float2*)(ws + ((size_t)8 << 20));         // 24 KiB (3072 twiddles)
  char*   sync = ws + ((size_t)8 << 20) + 32768;            // barrier counters + accs
  unsigned* bar  = (unsigned*)sync;                         // 16 counters (64 B)
  double*   accs = (double*)(sync + 128);                   // 36 doubles

  hipMemsetAsync(sync, 0, 512, stream);                     // zero bars + accs
  k_fused<<<NBLK, 256, 0, stream>>>(x, xr, tw, bar, accs, xl_s, out_xh, out_xl);
}

// Round 3
// 359.822 us; speedup vs baseline: 1.1001x; 1.1001x over previous
//
#include <hip/hip_runtime.h>
#include <math.h>

#define TLEN 2048
#define T2   4096
#define H2   2048
#define NBLK 512
#define EPS32 1.1920928955078125e-07

// agent-scope atomic load: always reads the coherent copy
__device__ __forceinline__ double ld_acc(const double* p){
  return __hip_atomic_load(p, __ATOMIC_RELAXED, __HIP_MEMORY_SCOPE_AGENT);
}

// ---- software grid barrier (512 co-resident blocks; distinct counter per use,
//      zeroed host-side via hipMemsetAsync each launch). Release/acquire fences
//      give cross-XCD visibility for plain stores (G16). Bounded spin: fail loud,
//      not hung. wait=false: arrive only (block is done with shared data). ----
__device__ __forceinline__ void gbar(unsigned* bar, bool wait = true){
  __syncthreads();
  if (threadIdx.x == 0){
    __threadfence();                          // release: wb dirty L2 -> coherent point
    __hip_atomic_fetch_add(bar, 1u, __ATOMIC_RELAXED, __HIP_MEMORY_SCOPE_AGENT);
    if (wait){
      unsigned spins = 0;
      while (__hip_atomic_load(bar, __ATOMIC_RELAXED, __HIP_MEMORY_SCOPE_AGENT) < NBLK){
        if (++spins > (1u << 20)) break;      // safety valve
        __builtin_amdgcn_s_sleep(8);
      }
      __threadfence();                        // acquire: invalidate stale lines
    }
  }
  __syncthreads();
}

// ---- 6-stage Stockham radix-4 FFT over 4096 pts in LDS.
//      Result lands in src0 (6 = even number of ping-pongs).
//      sgn=+1 forward, -1 inverse. Caller must __syncthreads() after filling src0.
__device__ __forceinline__ void fft_r4(float2* src0, float2* dst0,
                                       const float2* __restrict__ tw, float sgn){
  float2* src = src0; float2* dst = dst0;
  const int tid = threadIdx.x;
  #pragma unroll
  for (int st = 0; st < 6; ++st){
    const int sh = 2 * st;
    const int L = 1 << sh;
    const int Lmask = L - 1;
    #pragma unroll
    for (int bf = 0; bf < 4; ++bf){
      int idx = tid + (bf << 8);            // 0..1023
      int q  = idx & Lmask;
      int tb = idx ^ q;                     // p*L  (<= 1023)
      float2 a = src[idx];
      float2 b = src[idx + 1024];
      float2 c = src[idx + 2048];
      float2 d = src[idx + 3072];
      float2 w1 = tw[tb];
      float2 w2 = tw[2 * tb];
      float2 w3 = tw[3 * tb];
      float w1y = sgn * w1.y, w2y = sgn * w2.y, w3y = sgn * w3.y;
      float t0x = a.x + c.x, t0y = a.y + c.y;
      float t1x = a.x - c.x, t1y = a.y - c.y;
      float t2x = b.x + d.x, t2y = b.y + d.y;
      // fwd: -i*(b-d) = (y,-x); inv: +i*(b-d) = (-y,x)
      float t3x = sgn * (b.y - d.y);
      float t3y = -sgn * (b.x - d.x);
      float y0x = t0x + t2x, y0y = t0y + t2y;
      float y1x = t1x + t3x, y1y = t1y + t3y;
      float y2x = t0x - t2x, y2y = t0y - t2y;
      float y3x = t1x - t3x, y3y = t1y - t3y;
      int ob = q + (tb << 2);               // q + 4*p*L
      dst[ob]         = make_float2(y0x, y0y);
      dst[ob + L]     = make_float2(y1x * w1.x - y1y * w1y, y1x * w1y + y1y * w1.x);
      dst[ob + 2 * L] = make_float2(y2x * w2.x - y2y * w2y, y2x * w2y + y2y * w2.x);
      dst[ob + 3 * L] = make_float2(y3x * w3.x - y3y * w3y, y3x * w3y + y3y * w3.x);
    }
    __syncthreads();
    float2* t = src; src = dst; dst = t;
  }
}

// ---- block-reduce 9 doubles -> atomicAdd (agent scope) into accs[0..8] ----
__device__ __forceinline__ void reduce9(double* acc, double* red, double* accs){
  const int tid = threadIdx.x, wave = tid >> 6, lane = tid & 63;
  #pragma unroll
  for (int i = 0; i < 9; ++i){
    double v = acc[i];
    for (int off = 32; off; off >>= 1) v += __shfl_down(v, off);
    if (lane == 0) red[i * 4 + wave] = v;
  }
  __syncthreads();
  if (tid < 9)
    atomicAdd(&accs[tid], red[tid*4+0] + red[tid*4+1] + red[tid*4+2] + red[tid*4+3]);
}

// ---- per-bin 4-mode Gauss-Seidel chain, with stats ----
__device__ __forceinline__ void vmd_bin(float Fx, float Fy, float fj,
                                        const float* om, float* ux, float* uy,
                                        double* aFP, double* aP, double& aD){
  float sx = ux[0] + ux[1] + ux[2] + ux[3];
  float sy = uy[0] + uy[1] + uy[2] + uy[3];
  #pragma unroll
  for (int k = 0; k < 4; ++k){
    float ox = sx - ux[k], oy = sy - uy[k];
    float d = fj - om[k];
    float den = 1.0f + 2000.0f * d * d;
    float nx = (Fx - ox) / den, ny = (Fy - oy) / den;
    float pw = nx * nx + ny * ny;
    aFP[k] += (double)(fj * pw);
    aP[k]  += (double)pw;
    float ddx = nx - ux[k], ddy = ny - uy[k];
    aD += (double)(ddx * ddx + ddy * ddy);
    ux[k] = nx; uy[k] = ny;
    sx = ox + nx; sy = oy + ny;
  }
}

// ==== whole pipeline, one normally-launched kernel with software grid barriers ====
// 512 blocks x 256 thr; 64 KiB static LDS forces exactly 2 blocks/CU -> all resident.
// F (the positive-half spectrum) stays LDS-resident in bufA[0..2047] from the end
// of the forward FFT until the Hermitian build, so only u[8][4] (64 VGPRs) is ever
// live across phases -> no scratch spills (round-2 lesson: 78 MB of spill traffic).
__global__ void __launch_bounds__(256, 2)
k_fused(const float* __restrict__ x, float* __restrict__ xr,
        float2* __restrict__ tw, unsigned* __restrict__ bar,
        double* __restrict__ accs, float* __restrict__ xl_s,
        float* __restrict__ xh, float* __restrict__ xl){
  __shared__ float2 bufA[T2];
  __shared__ float2 bufB[T2];
  const int blk = blockIdx.x, tid = threadIdx.x;

  // ---- phase A: transpose x -> xr (blocks 0..255); twiddles (256..267) ----
  if (blk < 256){
    float (*tile)[65] = reinterpret_cast<float(*)[65]>(bufA);
    const int b = blk >> 5, t0 = (blk & 31) << 6, lo = tid & 63, r0 = tid >> 6;
    #pragma unroll
    for (int pass = 0; pass < 16; ++pass){
      int tt = r0 + (pass << 2);
      tile[tt][lo] = x[((size_t)(b * TLEN + t0 + tt)) * 64 + lo];
    }
    __syncthreads();
    #pragma unroll
    for (int pass = 0; pass < 16; ++pass){
      int c2 = r0 + (pass << 2);
      xr[((size_t)(b * 64 + c2)) * TLEN + t0 + lo] = tile[lo][c2];
    }
  } else if (blk < 268){
    int p = ((blk - 256) << 8) + tid;          // 0..3071 (radix-4 needs 3*tb <= 3069)
    double a = -6.283185307179586 * (double)p / 4096.0;
    tw[p] = make_float2((float)cos(a), (float)sin(a));
  }
  gbar(bar + 0);

  // ---- phase B: mirror-extend + forward FFT; spectrum stays in bufA ----
  {
    const float* f = xr + (size_t)blk * TLEN;
    #pragma unroll
    for (int pp = 0; pp < 16; ++pp){
      int i = tid + (pp << 8);
      int s = (i < 1024) ? (1023 - i) : ((i < 3072) ? (i - 1024) : (5119 - i));
      bufA[i] = make_float2(f[s], 0.0f);
    }
    __syncthreads();
    fft_r4(bufA, bufB, tw, 1.0f);              // result in bufA; F = bufA[0..2047]
  }
  // iter 1 (u starts at 0); F read from LDS
  float ux[8][4], uy[8][4];
  {
    const float om1[4] = {0.0f, 0.125f, 0.25f, 0.375f};
    double aFP[4] = {0,0,0,0}, aP[4] = {0,0,0,0}, aD = 0.0;
    #pragma unroll
    for (int pp = 0; pp < 8; ++pp){
      int j = tid + (pp << 8);
      float2 Fv = bufA[j];
      #pragma unroll
      for (int k = 0; k < 4; ++k){ ux[pp][k] = 0.0f; uy[pp][k] = 0.0f; }
      float fj = (float)j * (1.0f / 4096.0f);
      vmd_bin(Fv.x, Fv.y, fj, om1, ux[pp], uy[pp], aFP, aP, aD);
    }
    double acc[9] = {aFP[0],aFP[1],aFP[2],aFP[3],aP[0],aP[1],aP[2],aP[3],aD};
    reduce9(acc, (double*)bufB, accs);         // bufB scratch (FFT ping-pong is dead)
  }
  gbar(bar + 1);

  // ---- phase C: iters 2..4, u stays in registers, F stays in bufA ----
  bool active = true;
  double* slot = accs;                         // stats of last completed iter
  #pragma unroll 1
  for (int it = 0; it < 3; ++it){
    float om[4] = {0.f, 0.f, 0.f, 0.f};
    if (active){
      if (ld_acc(slot + 8) * (1.0 / 4096.0) + EPS32 > 5e-5){
        #pragma unroll
        for (int k = 0; k < 4; ++k)
          om[k] = (float)(ld_acc(slot + k) / ld_acc(slot + 4 + k));
      } else active = false;
    }
    if (active){
      double aFP[4] = {0,0,0,0}, aP[4] = {0,0,0,0}, aD = 0.0;
      #pragma unroll
      for (int pp = 0; pp < 8; ++pp){
        int j = tid + (pp << 8);
        float2 Fv = bufA[j];
        float fj = (float)j * (1.0f / 4096.0f);
        vmd_bin(Fv.x, Fv.y, fj, om, ux[pp], uy[pp], aFP, aP, aD);
      }
      double acc[9] = {aFP[0],aFP[1],aFP[2],aFP[3],aP[0],aP[1],aP[2],aP[3],aD};
      reduce9(acc, (double*)bufB, slot + 9);
    }
    gbar(bar + 2 + it);
    slot += 9;
  }

  // ---- phase D: guarded iter-5 mode-0 update + Hermitian build into bufB,
  //      then inverse FFT with (bufB, bufA) -> result lands in bufB ----
  {
    bool act = active;
    float om0 = 0.0f;
    if (act){
      if (ld_acc(slot + 8) * (1.0 / 4096.0) + EPS32 > 5e-5)
        om0 = (float)(ld_acc(slot) / ld_acc(slot + 4));
      else act = false;
    }
    #pragma unroll
    for (int pp = 0; pp < 8; ++pp){
      int j = tid + (pp << 8);
      float vx, vy;
      if (act){                 // u0^(5) = (F - sum_{k>0} u_k^(4)) / den
        float2 Fv = bufA[j];
        float sx = ux[pp][1] + ux[pp][2] + ux[pp][3];
        float sy = uy[pp][1] + uy[pp][2] + uy[pp][3];
        float fj = (float)j * (1.0f / 4096.0f);
        float dd = fj - om0;
        float den = 1.0f + 2000.0f * dd * dd;
        vx = (Fv.x - sx) / den; vy = (Fv.y - sy) / den;
      } else {
        vx = ux[pp][0]; vy = uy[pp][0];
      }
      if (j == 0){
        bufB[0] = make_float2(vx, -vy);               // S[0] = conj(U[0])
      } else {
        bufB[j]      = make_float2(vx, vy);           // S[j] = U[j]
        bufB[T2 - j] = make_float2(vx, -vy);          // S[4096-j] = conj(U[j])
      }
      if (j == H2 - 1) bufB[H2] = make_float2(vx, -vy); // S[2048] = conj(U[2047])
    }
    __syncthreads();
    fft_r4(bufB, bufA, tw, -1.0f);                    // result in bufB
    const float scale = 1.0f / (float)T2;
    #pragma unroll
    for (int pp = 0; pp < 8; ++pp){
      int t = tid + (pp << 8);
      xl_s[(size_t)blk * TLEN + t] = bufB[1024 + t].x * scale;
    }
  }
  // blocks >= 256 have no phase-E work: arrive without spinning and exit
  gbar(bar + 5, blk < 256);
  if (blk >= 256) return;

  // ---- phase E: transpose back + x_h = x - x_l (blocks 0..255) ----
  {
    float (*tile)[65] = reinterpret_cast<float(*)[65]>(bufA);
    const int b = blk >> 5, t0 = (blk & 31) << 6, lo = tid & 63, r0 = tid >> 6;
    #pragma unroll
    for (int pass = 0; pass < 16; ++pass){
      int c2 = r0 + (pass << 2);
      tile[c2][lo] = xl_s[((size_t)(b * 64 + c2)) * TLEN + t0 + lo];
    }
    __syncthreads();
    #pragma unroll
    for (int pass = 0; pass < 16; ++pass){
      int tt = r0 + (pass << 2);
      size_t oi = ((size_t)(b * TLEN + t0 + tt)) * 64 + lo;
      float xlv = tile[lo][tt];
      float xv  = x[oi];
      xh[oi] = xv - xlv;
      xl[oi] = xlv;
    }
  }
}

extern "C" void kernel_launch(void* const* d_in, const int* in_sizes, int n_in,
                              void* d_out, int out_size, void* d_ws, size_t ws_size,
                              hipStream_t stream){
  const float* x = (const float*)d_in[0];
  float* out_xh = (float*)d_out;
  float* out_xl = out_xh + (size_t)8 * TLEN * 64;

  char* ws = (char*)d_ws;
  float*  xr   = (float*)ws;                                // 4 MiB
  float*  xl_s = (float*)(ws + ((size_t)4 << 20));          // 4 MiB
  float2* tw   = (float2*)(ws + ((size_t)8 << 20));         // 24 KiB (3072 twiddles)
  char*   sync = ws + ((size_t)8 << 20) + 32768;            // barrier counters + accs
  unsigned* bar  = (unsigned*)sync;                         // 16 counters (64 B)
  double*   accs = (double*)(sync + 128);                   // 36 doubles

  hipMemsetAsync(sync, 0, 512, stream);                     // zero bars + accs
  k_fused<<<NBLK, 256, 0, stream>>>(x, xr, tw, bar, accs, xl_s, out_xh, out_xl);
}

// Round 4
// 271.276 us; speedup vs baseline: 1.4592x; 1.3264x over previous
//
#include <hip/hip_runtime.h>
#include <math.h>

#define TLEN 2048
#define T2   4096
#define H2   2048
#define NBLK 512
#define EPS32 1.1920928955078125e-07

// agent-scope atomic load: always reads the coherent copy
__device__ __forceinline__ double ld_acc(const double* p){
  return __hip_atomic_load(p, __ATOMIC_RELAXED, __HIP_MEMORY_SCOPE_AGENT);
}

// ---- software grid barrier (512 co-resident blocks; distinct counter per use,
//      zeroed host-side via hipMemsetAsync each launch).
//      fence=true: full release/acquire (L2 wb/inv) for plain cross-block stores
//                  (needed only around xr and xl_s hand-offs).
//      fence=false: pure counter barrier — sufficient when the only shared data
//                  is accs, written by device-scope atomics (already coherent)
//                  and read via agent-scope atomic loads. __syncthreads() drains
//                  each thread's outstanding memory ops before arrival.
//      wait=false: arrive only (block produces nothing the others consume later).
__device__ __forceinline__ void gbar(unsigned* bar, bool fence, bool wait = true){
  __syncthreads();
  if (threadIdx.x == 0){
    if (fence) __threadfence();               // release: wb dirty L2
    __hip_atomic_fetch_add(bar, 1u, __ATOMIC_RELAXED, __HIP_MEMORY_SCOPE_AGENT);
    if (wait){
      unsigned spins = 0;
      while (__hip_atomic_load(bar, __ATOMIC_RELAXED, __HIP_MEMORY_SCOPE_AGENT) < NBLK){
        if (++spins > (1u << 20)) break;      // safety valve: fail loud, not hung
        __builtin_amdgcn_s_sleep(8);
      }
      if (fence) __threadfence();             // acquire: invalidate stale lines
    }
  }
  __syncthreads();
}

// ---- 6-stage Stockham radix-4 FFT over 4096 pts in LDS.
//      Result lands in src0 (6 = even number of ping-pongs).
//      sgn=+1 forward, -1 inverse. Caller must __syncthreads() after filling src0.
__device__ __forceinline__ void fft_r4(float2* src0, float2* dst0,
                                       const float2* __restrict__ tw, float sgn){
  float2* src = src0; float2* dst = dst0;
  const int tid = threadIdx.x;
  #pragma unroll
  for (int st = 0; st < 6; ++st){
    const int sh = 2 * st;
    const int L = 1 << sh;
    const int Lmask = L - 1;
    #pragma unroll
    for (int bf = 0; bf < 4; ++bf){
      int idx = tid + (bf << 8);            // 0..1023
      int q  = idx & Lmask;
      int tb = idx ^ q;                     // p*L  (<= 1023)
      float2 a = src[idx];
      float2 b = src[idx + 1024];
      float2 c = src[idx + 2048];
      float2 d = src[idx + 3072];
      float2 w1 = tw[tb];
      float2 w2 = tw[2 * tb];
      float2 w3 = tw[3 * tb];
      float w1y = sgn * w1.y, w2y = sgn * w2.y, w3y = sgn * w3.y;
      float t0x = a.x + c.x, t0y = a.y + c.y;
      float t1x = a.x - c.x, t1y = a.y - c.y;
      float t2x = b.x + d.x, t2y = b.y + d.y;
      // fwd: -i*(b-d) = (y,-x); inv: +i*(b-d) = (-y,x)
      float t3x = sgn * (b.y - d.y);
      float t3y = -sgn * (b.x - d.x);
      float y0x = t0x + t2x, y0y = t0y + t2y;
      float y1x = t1x + t3x, y1y = t1y + t3y;
      float y2x = t0x - t2x, y2y = t0y - t2y;
      float y3x = t1x - t3x, y3y = t1y - t3y;
      int ob = q + (tb << 2);               // q + 4*p*L
      dst[ob]         = make_float2(y0x, y0y);
      dst[ob + L]     = make_float2(y1x * w1.x - y1y * w1y, y1x * w1y + y1y * w1.x);
      dst[ob + 2 * L] = make_float2(y2x * w2.x - y2y * w2y, y2x * w2y + y2y * w2.x);
      dst[ob + 3 * L] = make_float2(y3x * w3.x - y3y * w3y, y3x * w3y + y3y * w3.x);
    }
    __syncthreads();
    float2* t = src; src = dst; dst = t;
  }
}

// ---- block-reduce 9 doubles -> atomicAdd (agent scope) into accs[0..8] ----
__device__ __forceinline__ void reduce9(double* acc, double* red, double* accs){
  const int tid = threadIdx.x, wave = tid >> 6, lane = tid & 63;
  #pragma unroll
  for (int i = 0; i < 9; ++i){
    double v = acc[i];
    for (int off = 32; off; off >>= 1) v += __shfl_down(v, off);
    if (lane == 0) red[i * 4 + wave] = v;
  }
  __syncthreads();
  if (tid < 9)
    atomicAdd(&accs[tid], red[tid*4+0] + red[tid*4+1] + red[tid*4+2] + red[tid*4+3]);
}

// ---- per-bin 4-mode Gauss-Seidel chain, with stats ----
__device__ __forceinline__ void vmd_bin(float Fx, float Fy, float fj,
                                        const float* om, float* ux, float* uy,
                                        double* aFP, double* aP, double& aD){
  float sx = ux[0] + ux[1] + ux[2] + ux[3];
  float sy = uy[0] + uy[1] + uy[2] + uy[3];
  #pragma unroll
  for (int k = 0; k < 4; ++k){
    float ox = sx - ux[k], oy = sy - uy[k];
    float d = fj - om[k];
    float den = 1.0f + 2000.0f * d * d;
    float nx = (Fx - ox) / den, ny = (Fy - oy) / den;
    float pw = nx * nx + ny * ny;
    aFP[k] += (double)(fj * pw);
    aP[k]  += (double)pw;
    float ddx = nx - ux[k], ddy = ny - uy[k];
    aD += (double)(ddx * ddx + ddy * ddy);
    ux[k] = nx; uy[k] = ny;
    sx = ox + nx; sy = oy + ny;
  }
}

// ==== whole pipeline, one normally-launched kernel with software grid barriers ====
// 512 blocks x 256 thr; 64 KiB static LDS forces exactly 2 blocks/CU -> all resident.
// waves_per_eu(2,2): LDS already caps occupancy at 2 waves/EU, so tell the register
// allocator it may use the full 256-VGPR budget — round-3 lesson: the default
// 128-VGPR occupancy target spilled the u state (42 MB of scratch writebacks).
__global__ void __attribute__((amdgpu_flat_work_group_size(256, 256),
                               amdgpu_waves_per_eu(2, 2)))
k_fused(const float* __restrict__ x, float* __restrict__ xr,
        float2* __restrict__ tw, unsigned* __restrict__ bar,
        double* __restrict__ accs, float* __restrict__ xl_s,
        float* __restrict__ xh, float* __restrict__ xl){
  __shared__ float2 bufA[T2];
  __shared__ float2 bufB[T2];
  const int blk = blockIdx.x, tid = threadIdx.x;

  // ---- phase A: transpose x -> xr (blocks 0..255); twiddles (256..267) ----
  if (blk < 256){
    float (*tile)[65] = reinterpret_cast<float(*)[65]>(bufA);
    const int b = blk >> 5, t0 = (blk & 31) << 6, lo = tid & 63, r0 = tid >> 6;
    #pragma unroll
    for (int pass = 0; pass < 16; ++pass){
      int tt = r0 + (pass << 2);
      tile[tt][lo] = x[((size_t)(b * TLEN + t0 + tt)) * 64 + lo];
    }
    __syncthreads();
    #pragma unroll
    for (int pass = 0; pass < 16; ++pass){
      int c2 = r0 + (pass << 2);
      xr[((size_t)(b * 64 + c2)) * TLEN + t0 + lo] = tile[lo][c2];
    }
  } else if (blk < 268){
    int p = ((blk - 256) << 8) + tid;          // 0..3071 (radix-4 needs 3*tb <= 3069)
    double a = -6.283185307179586 * (double)p / 4096.0;
    tw[p] = make_float2((float)cos(a), (float)sin(a));
  }
  gbar(bar + 0, true);                         // full fence: plain xr/tw hand-off

  // ---- phase B: mirror-extend + forward FFT; spectrum stays in bufA ----
  {
    const float* f = xr + (size_t)blk * TLEN;
    #pragma unroll
    for (int pp = 0; pp < 16; ++pp){
      int i = tid + (pp << 8);
      int s = (i < 1024) ? (1023 - i) : ((i < 3072) ? (i - 1024) : (5119 - i));
      bufA[i] = make_float2(f[s], 0.0f);
    }
    __syncthreads();
    fft_r4(bufA, bufB, tw, 1.0f);              // result in bufA; F = bufA[0..2047]
  }
  // iter 1 (u starts at 0); F read from LDS
  float ux[8][4], uy[8][4];
  {
    const float om1[4] = {0.0f, 0.125f, 0.25f, 0.375f};
    double aFP[4] = {0,0,0,0}, aP[4] = {0,0,0,0}, aD = 0.0;
    #pragma unroll
    for (int pp = 0; pp < 8; ++pp){
      int j = tid + (pp << 8);
      float2 Fv = bufA[j];
      #pragma unroll
      for (int k = 0; k < 4; ++k){ ux[pp][k] = 0.0f; uy[pp][k] = 0.0f; }
      float fj = (float)j * (1.0f / 4096.0f);
      vmd_bin(Fv.x, Fv.y, fj, om1, ux[pp], uy[pp], aFP, aP, aD);
    }
    double acc[9] = {aFP[0],aFP[1],aFP[2],aFP[3],aP[0],aP[1],aP[2],aP[3],aD};
    reduce9(acc, (double*)bufB, accs);         // bufB scratch (FFT ping-pong is dead)
  }
  gbar(bar + 1, false);                        // accs only -> counter barrier

  // ---- phase C: iters 2..4, u stays in registers, F stays in bufA ----
  bool active = true;
  double* slot = accs;                         // stats of last completed iter
  #pragma unroll 1
  for (int it = 0; it < 3; ++it){
    float om[4] = {0.f, 0.f, 0.f, 0.f};
    if (active){
      if (ld_acc(slot + 8) * (1.0 / 4096.0) + EPS32 > 5e-5){
        #pragma unroll
        for (int k = 0; k < 4; ++k)
          om[k] = (float)(ld_acc(slot + k) / ld_acc(slot + 4 + k));
      } else active = false;
    }
    if (active){
      double aFP[4] = {0,0,0,0}, aP[4] = {0,0,0,0}, aD = 0.0;
      #pragma unroll
      for (int pp = 0; pp < 8; ++pp){
        int j = tid + (pp << 8);
        float2 Fv = bufA[j];
        float fj = (float)j * (1.0f / 4096.0f);
        vmd_bin(Fv.x, Fv.y, fj, om, ux[pp], uy[pp], aFP, aP, aD);
      }
      double acc[9] = {aFP[0],aFP[1],aFP[2],aFP[3],aP[0],aP[1],aP[2],aP[3],aD};
      reduce9(acc, (double*)bufB, slot + 9);
    }
    gbar(bar + 2 + it, false);                 // accs only -> counter barrier
    slot += 9;
  }

  // ---- phase D: guarded iter-5 mode-0 update + Hermitian build into bufB,
  //      then inverse FFT with (bufB, bufA) -> result lands in bufB ----
  {
    bool act = active;
    float om0 = 0.0f;
    if (act){
      if (ld_acc(slot + 8) * (1.0 / 4096.0) + EPS32 > 5e-5)
        om0 = (float)(ld_acc(slot) / ld_acc(slot + 4));
      else act = false;
    }
    #pragma unroll
    for (int pp = 0; pp < 8; ++pp){
      int j = tid + (pp << 8);
      float vx, vy;
      if (act){                 // u0^(5) = (F - sum_{k>0} u_k^(4)) / den
        float2 Fv = bufA[j];
        float sx = ux[pp][1] + ux[pp][2] + ux[pp][3];
        float sy = uy[pp][1] + uy[pp][2] + uy[pp][3];
        float fj = (float)j * (1.0f / 4096.0f);
        float dd = fj - om0;
        float den = 1.0f + 2000.0f * dd * dd;
        vx = (Fv.x - sx) / den; vy = (Fv.y - sy) / den;
      } else {
        vx = ux[pp][0]; vy = uy[pp][0];
      }
      if (j == 0){
        bufB[0] = make_float2(vx, -vy);               // S[0] = conj(U[0])
      } else {
        bufB[j]      = make_float2(vx, vy);           // S[j] = U[j]
        bufB[T2 - j] = make_float2(vx, -vy);          // S[4096-j] = conj(U[j])
      }
      if (j == H2 - 1) bufB[H2] = make_float2(vx, -vy); // S[2048] = conj(U[2047])
    }
    __syncthreads();
    fft_r4(bufB, bufA, tw, -1.0f);                    // result in bufB
    const float scale = 1.0f / (float)T2;
    #pragma unroll
    for (int pp = 0; pp < 8; ++pp){
      int t = tid + (pp << 8);
      xl_s[(size_t)blk * TLEN + t] = bufB[1024 + t].x * scale;
    }
  }
  // blocks >= 256 have no phase-E work: arrive without spinning and exit
  gbar(bar + 5, true, blk < 256);              // full fence: plain xl_s hand-off
  if (blk >= 256) return;

  // ---- phase E: transpose back + x_h = x - x_l (blocks 0..255) ----
  {
    float (*tile)[65] = reinterpret_cast<float(*)[65]>(bufA);
    const int b = blk >> 5, t0 = (blk & 31) << 6, lo = tid & 63, r0 = tid >> 6;
    #pragma unroll
    for (int pass = 0; pass < 16; ++pass){
      int c2 = r0 + (pass << 2);
      tile[c2][lo] = xl_s[((size_t)(b * 64 + c2)) * TLEN + t0 + lo];
    }
    __syncthreads();
    #pragma unroll
    for (int pass = 0; pass < 16; ++pass){
      int tt = r0 + (pass << 2);
      size_t oi = ((size_t)(b * TLEN + t0 + tt)) * 64 + lo;
      float xlv = tile[lo][tt];
      float xv  = x[oi];
      xh[oi] = xv - xlv;
      xl[oi] = xlv;
    }
  }
}

extern "C" void kernel_launch(void* const* d_in, const int* in_sizes, int n_in,
                              void* d_out, int out_size, void* d_ws, size_t ws_size,
                              hipStream_t stream){
  const float* x = (const float*)d_in[0];
  float* out_xh = (float*)d_out;
  float* out_xl = out_xh + (size_t)8 * TLEN * 64;

  char* ws = (char*)d_ws;
  float*  xr   = (float*)ws;                                // 4 MiB
  float*  xl_s = (float*)(ws + ((size_t)4 << 20));          // 4 MiB
  float2* tw   = (float2*)(ws + ((size_t)8 << 20));         // 24 KiB (3072 twiddles)
  char*   sync = ws + ((size_t)8 << 20) + 32768;            // barrier counters + accs
  unsigned* bar  = (unsigned*)sync;                         // 16 counters (64 B)
  double*   accs = (double*)(sync + 128);                   // 36 doubles

  hipMemsetAsync(sync, 0, 512, stream);                     // zero bars + accs
  k_fused<<<NBLK, 256, 0, stream>>>(x, xr, tw, bar, accs, xl_s, out_xh, out_xl);
}

// Round 5
// 255.361 us; speedup vs baseline: 1.5502x; 1.0623x over previous
//
#include <hip/hip_runtime.h>
#include <math.h>

#define TLEN 2048
#define T2   4096
#define H2   2048
#define NBLK 512
#define EPS32 1.1920928955078125e-07

// agent-scope atomic load: always reads the coherent copy
__device__ __forceinline__ double ld_acc(const double* p){
  return __hip_atomic_load(p, __ATOMIC_RELAXED, __HIP_MEMORY_SCOPE_AGENT);
}

// ---- software grid barrier (512 co-resident blocks; distinct counter per use,
//      zeroed host-side via hipMemsetAsync). fence=true only around plain-store
//      hand-offs (xr, xl_s); accs-only barriers are pure counter barriers. ----
__device__ __forceinline__ void gbar(unsigned* bar, bool fence, bool wait = true){
  __syncthreads();
  if (threadIdx.x == 0){
    if (fence) __threadfence();               // release: wb dirty L2
    __hip_atomic_fetch_add(bar, 1u, __ATOMIC_RELAXED, __HIP_MEMORY_SCOPE_AGENT);
    if (wait){
      unsigned spins = 0;
      while (__hip_atomic_load(bar, __ATOMIC_RELAXED, __HIP_MEMORY_SCOPE_AGENT) < NBLK){
        if (++spins > (1u << 20)) break;      // safety valve: fail loud, not hung
        __builtin_amdgcn_s_sleep(32);         // ~2k cycles/poll: cut poll traffic
      }
      if (fence) __threadfence();             // acquire: invalidate stale lines
    }
  }
  __syncthreads();
}

// ---- 6-stage Stockham radix-4 FFT over 4096 pts in LDS.
//      Result lands in src0 (6 = even number of ping-pongs).
//      sgn=+1 forward, -1 inverse. Caller must __syncthreads() after filling src0.
__device__ __forceinline__ void fft_r4(float2* src0, float2* dst0,
                                       const float2* __restrict__ tw, float sgn){
  float2* src = src0; float2* dst = dst0;
  const int tid = threadIdx.x;
  #pragma unroll
  for (int st = 0; st < 6; ++st){
    const int sh = 2 * st;
    const int L = 1 << sh;
    const int Lmask = L - 1;
    #pragma unroll
    for (int bf = 0; bf < 4; ++bf){
      int idx = tid + (bf << 8);            // 0..1023
      int q  = idx & Lmask;
      int tb = idx ^ q;                     // p*L  (<= 1023)
      float2 a = src[idx];
      float2 b = src[idx + 1024];
      float2 c = src[idx + 2048];
      float2 d = src[idx + 3072];
      float2 w1 = tw[tb];
      float2 w2 = tw[2 * tb];
      float2 w3 = tw[3 * tb];
      float w1y = sgn * w1.y, w2y = sgn * w2.y, w3y = sgn * w3.y;
      float t0x = a.x + c.x, t0y = a.y + c.y;
      float t1x = a.x - c.x, t1y = a.y - c.y;
      float t2x = b.x + d.x, t2y = b.y + d.y;
      // fwd: -i*(b-d) = (y,-x); inv: +i*(b-d) = (-y,x)
      float t3x = sgn * (b.y - d.y);
      float t3y = -sgn * (b.x - d.x);
      float y0x = t0x + t2x, y0y = t0y + t2y;
      float y1x = t1x + t3x, y1y = t1y + t3y;
      float y2x = t0x - t2x, y2y = t0y - t2y;
      float y3x = t1x - t3x, y3y = t1y - t3y;
      int ob = q + (tb << 2);               // q + 4*p*L
      dst[ob]         = make_float2(y0x, y0y);
      dst[ob + L]     = make_float2(y1x * w1.x - y1y * w1y, y1x * w1y + y1y * w1.x);
      dst[ob + 2 * L] = make_float2(y2x * w2.x - y2y * w2y, y2x * w2y + y2y * w2.x);
      dst[ob + 3 * L] = make_float2(y3x * w3.x - y3y * w3y, y3x * w3y + y3y * w3.x);
    }
    __syncthreads();
    float2* t = src; src = dst; dst = t;
  }
}

// ---- wave-64 shuffle sum ----
__device__ __forceinline__ double wred(double v){
  #pragma unroll
  for (int off = 32; off; off >>= 1) v += __shfl_down(v, off);
  return v;
}

// ---- reduce 9 named doubles (by value — no local array!) -> atomicAdd accs ----
__device__ __forceinline__ void red9(double a0, double a1, double a2, double a3,
                                     double a4, double a5, double a6, double a7,
                                     double a8, double* red, double* accs){
  const int tid = threadIdx.x, wave = tid >> 6, lane = tid & 63;
  double r;
  r = wred(a0); if (lane == 0) red[ 0 + wave] = r;
  r = wred(a1); if (lane == 0) red[ 4 + wave] = r;
  r = wred(a2); if (lane == 0) red[ 8 + wave] = r;
  r = wred(a3); if (lane == 0) red[12 + wave] = r;
  r = wred(a4); if (lane == 0) red[16 + wave] = r;
  r = wred(a5); if (lane == 0) red[20 + wave] = r;
  r = wred(a6); if (lane == 0) red[24 + wave] = r;
  r = wred(a7); if (lane == 0) red[28 + wave] = r;
  r = wred(a8); if (lane == 0) red[32 + wave] = r;
  __syncthreads();
  if (tid < 9)
    atomicAdd(&accs[tid], red[tid*4+0] + red[tid*4+1] + red[tid*4+2] + red[tid*4+3]);
}

// ==== round-4 lesson: per-thread ARRAYS (u[8][4], acc[9], om[4]) were kept in
// scratch by the compiler (42 MB of HBM writebacks, VGPR stuck at 128 under two
// different occupancy directives). All per-thread state is now NAMED variables:
// 16 float4s + 9 scalar doubles. Component access .x/.y/.z/.w is always static.

// one mode update with stats; locals in scope: fj,Fx,Fy,sx,sy,aD,aFP*,aP*
#define MODE_S(UXc, UYc, OMc, AFP, AP) {                       \
  float ox_ = sx - (UXc), oy_ = sy - (UYc);                    \
  float d_  = fj - (OMc);                                      \
  float den_ = 1.0f + 2000.0f * d_ * d_;                       \
  float nx_ = (Fx - ox_) / den_, ny_ = (Fy - oy_) / den_;      \
  float pw_ = nx_ * nx_ + ny_ * ny_;                           \
  AFP += (double)(fj * pw_);  AP += (double)pw_;               \
  float ddx_ = nx_ - (UXc), ddy_ = ny_ - (UYc);                \
  aD += (double)(ddx_ * ddx_ + ddy_ * ddy_);                   \
  (UXc) = nx_; (UYc) = ny_;                                    \
  sx = ox_ + nx_; sy = oy_ + ny_; }

// full 4-mode Gauss-Seidel chain on this thread's bin PP; F read from bufA
#define BIN_S(PP, UX, UY) {                                    \
  int j = tid + ((PP) << 8);                                   \
  float2 Fv = bufA[j];                                         \
  float Fx = Fv.x, Fy = Fv.y;                                  \
  float fj = (float)j * (1.0f / 4096.0f);                      \
  float sx = UX.x + UX.y + UX.z + UX.w;                        \
  float sy = UY.x + UY.y + UY.z + UY.w;                        \
  MODE_S(UX.x, UY.x, om.x, aFP0, aP0)                          \
  MODE_S(UX.y, UY.y, om.y, aFP1, aP1)                          \
  MODE_S(UX.z, UY.z, om.z, aFP2, aP2)                          \
  MODE_S(UX.w, UY.w, om.w, aFP3, aP3) }

#define IT1(PP, UX, UY) { UX = make_float4(0.f,0.f,0.f,0.f);   \
                          UY = make_float4(0.f,0.f,0.f,0.f);   \
                          BIN_S(PP, UX, UY) }

// iter-5 mode-0 update + Hermitian store into bufB
#define HERM(PP, UX, UY) {                                     \
  int j = tid + ((PP) << 8);                                   \
  float vx, vy;                                                \
  if (act){                                                    \
    float2 Fv = bufA[j];                                       \
    float sx = UX.y + UX.z + UX.w;                             \
    float sy = UY.y + UY.z + UY.w;                             \
    float fj = (float)j * (1.0f / 4096.0f);                    \
    float dd = fj - om0;                                       \
    float den = 1.0f + 2000.0f * dd * dd;                      \
    vx = (Fv.x - sx) / den; vy = (Fv.y - sy) / den;            \
  } else { vx = UX.x; vy = UY.x; }                             \
  if (j == 0){ bufB[0] = make_float2(vx, -vy); }               \
  else { bufB[j]      = make_float2(vx, vy);                   \
         bufB[T2 - j] = make_float2(vx, -vy); }                \
  if (j == H2 - 1) bufB[H2] = make_float2(vx, -vy); }

#define FOR8(M) M(0,ux0,uy0) M(1,ux1,uy1) M(2,ux2,uy2) M(3,ux3,uy3) \
                M(4,ux4,uy4) M(5,ux5,uy5) M(6,ux6,uy6) M(7,ux7,uy7)

// ==== whole pipeline, one normally-launched kernel with software grid barriers ====
// 512 blocks x 256 thr; 64 KiB static LDS forces exactly 2 blocks/CU -> all resident.
__global__ void __attribute__((amdgpu_flat_work_group_size(256, 256),
                               amdgpu_waves_per_eu(2, 2)))
k_fused(const float* __restrict__ x, float* __restrict__ xr,
        float2* __restrict__ tw, unsigned* __restrict__ bar,
        double* __restrict__ accs, float* __restrict__ xl_s,
        float* __restrict__ xh, float* __restrict__ xl){
  __shared__ float2 bufA[T2];
  __shared__ float2 bufB[T2];
  const int blk = blockIdx.x, tid = threadIdx.x;

  // ---- phase A: transpose x -> xr (blocks 0..255); twiddles (256..267) ----
  if (blk < 256){
    float (*tile)[65] = reinterpret_cast<float(*)[65]>(bufA);
    const int b = blk >> 5, t0 = (blk & 31) << 6, lo = tid & 63, r0 = tid >> 6;
    #pragma unroll
    for (int pass = 0; pass < 16; ++pass){
      int tt = r0 + (pass << 2);
      tile[tt][lo] = x[((size_t)(b * TLEN + t0 + tt)) * 64 + lo];
    }
    __syncthreads();
    #pragma unroll
    for (int pass = 0; pass < 16; ++pass){
      int c2 = r0 + (pass << 2);
      xr[((size_t)(b * 64 + c2)) * TLEN + t0 + lo] = tile[lo][c2];
    }
  } else if (blk < 268){
    int p = ((blk - 256) << 8) + tid;          // 0..3071 (radix-4 needs 3*tb <= 3069)
    double a = -6.283185307179586 * (double)p / 4096.0;
    tw[p] = make_float2((float)cos(a), (float)sin(a));
  }
  gbar(bar + 0, true);                         // full fence: plain xr/tw hand-off

  // ---- phase B: mirror-extend + forward FFT; spectrum stays in bufA ----
  {
    const float* f = xr + (size_t)blk * TLEN;
    #pragma unroll
    for (int pp = 0; pp < 16; ++pp){
      int i = tid + (pp << 8);
      int s = (i < 1024) ? (1023 - i) : ((i < 3072) ? (i - 1024) : (5119 - i));
      bufA[i] = make_float2(f[s], 0.0f);
    }
    __syncthreads();
    fft_r4(bufA, bufB, tw, 1.0f);              // result in bufA; F = bufA[0..2047]
  }

  float4 ux0, ux1, ux2, ux3, ux4, ux5, ux6, ux7;
  float4 uy0, uy1, uy2, uy3, uy4, uy5, uy6, uy7;
  float4 om = make_float4(0.0f, 0.125f, 0.25f, 0.375f);

  // iter 1 (u starts at 0); F read from LDS
  {
    double aFP0=0,aFP1=0,aFP2=0,aFP3=0,aP0=0,aP1=0,aP2=0,aP3=0,aD=0;
    FOR8(IT1)
    red9(aFP0,aFP1,aFP2,aFP3,aP0,aP1,aP2,aP3,aD, (double*)bufB, accs);
  }
  gbar(bar + 1, false);                        // accs only -> counter barrier

  // ---- phase C: iters 2..4, u stays in registers, F stays in bufA ----
  bool active = true;
  double* slot = accs;                         // stats of last completed iter
  #pragma unroll 1
  for (int it = 0; it < 3; ++it){
    if (active){
      if (ld_acc(slot + 8) * (1.0 / 4096.0) + EPS32 > 5e-5){
        om.x = (float)(ld_acc(slot + 0) / ld_acc(slot + 4));
        om.y = (float)(ld_acc(slot + 1) / ld_acc(slot + 5));
        om.z = (float)(ld_acc(slot + 2) / ld_acc(slot + 6));
        om.w = (float)(ld_acc(slot + 3) / ld_acc(slot + 7));
      } else active = false;
    }
    if (active){
      double aFP0=0,aFP1=0,aFP2=0,aFP3=0,aP0=0,aP1=0,aP2=0,aP3=0,aD=0;
      FOR8(BIN_S)
      red9(aFP0,aFP1,aFP2,aFP3,aP0,aP1,aP2,aP3,aD, (double*)bufB, slot + 9);
    }
    gbar(bar + 2 + it, false);                 // accs only -> counter barrier
    slot += 9;
  }

  // ---- phase D: guarded iter-5 mode-0 update + Hermitian build into bufB,
  //      then inverse FFT with (bufB, bufA) -> result lands in bufB ----
  {
    bool act = active;
    float om0 = 0.0f;
    if (act){
      if (ld_acc(slot + 8) * (1.0 / 4096.0) + EPS32 > 5e-5)
        om0 = (float)(ld_acc(slot) / ld_acc(slot + 4));
      else act = false;
    }
    FOR8(HERM)
    __syncthreads();
    fft_r4(bufB, bufA, tw, -1.0f);                    // result in bufB
    const float scale = 1.0f / (float)T2;
    #pragma unroll
    for (int pp = 0; pp < 8; ++pp){
      int t = tid + (pp << 8);
      xl_s[(size_t)blk * TLEN + t] = bufB[1024 + t].x * scale;
    }
  }
  // blocks >= 256 have no phase-E work: arrive without spinning and exit
  gbar(bar + 5, true, blk < 256);              // full fence: plain xl_s hand-off
  if (blk >= 256) return;

  // ---- phase E: transpose back + x_h = x - x_l (blocks 0..255) ----
  {
    float (*tile)[65] = reinterpret_cast<float(*)[65]>(bufA);
    const int b = blk >> 5, t0 = (blk & 31) << 6, lo = tid & 63, r0 = tid >> 6;
    #pragma unroll
    for (int pass = 0; pass < 16; ++pass){
      int c2 = r0 + (pass << 2);
      tile[c2][lo] = xl_s[((size_t)(b * 64 + c2)) * TLEN + t0 + lo];
    }
    __syncthreads();
    #pragma unroll
    for (int pass = 0; pass < 16; ++pass){
      int tt = r0 + (pass << 2);
      size_t oi = ((size_t)(b * TLEN + t0 + tt)) * 64 + lo;
      float xlv = tile[lo][tt];
      float xv  = x[oi];
      xh[oi] = xv - xlv;
      xl[oi] = xlv;
    }
  }
}

extern "C" void kernel_launch(void* const* d_in, const int* in_sizes, int n_in,
                              void* d_out, int out_size, void* d_ws, size_t ws_size,
                              hipStream_t stream){
  const float* x = (const float*)d_in[0];
  float* out_xh = (float*)d_out;
  float* out_xl = out_xh + (size_t)8 * TLEN * 64;

  char* ws = (char*)d_ws;
  float*  xr   = (float*)ws;                                // 4 MiB
  float*  xl_s = (float*)(ws + ((size_t)4 << 20));          // 4 MiB
  float2* tw   = (float2*)(ws + ((size_t)8 << 20));         // 24 KiB (3072 twiddles)
  char*   sync = ws + ((size_t)8 << 20) + 32768;            // barrier counters + accs
  unsigned* bar  = (unsigned*)sync;                         // 16 counters (64 B)
  double*   accs = (double*)(sync + 128);                   // 36 doubles

  hipMemsetAsync(sync, 0, 512, stream);                     // zero bars + accs
  k_fused<<<NBLK, 256, 0, stream>>>(x, xr, tw, bar, accs, xl_s, out_xh, out_xl);
}

// Round 6
// 179.877 us; speedup vs baseline: 2.2007x; 1.4196x over previous
//
#include <hip/hip_runtime.h>
#include <math.h>

#define TLEN 2048
#define T2   4096
#define H2   2048
#define NBLK 512
#define EPS32 1.1920928955078125e-07

// agent-scope atomic load: always reads the coherent copy
__device__ __forceinline__ double ld_acc(const double* p){
  return __hip_atomic_load(p, __ATOMIC_RELAXED, __HIP_MEMORY_SCOPE_AGENT);
}

// ---- pure counter grid barrier (512 co-resident blocks; distinct counter per
//      use, zeroed host-side). NO threadfence: the only cross-block data is accs,
//      written by agent-scope atomicAdd (already at the coherent point) and read
//      via agent-scope atomic loads. __syncthreads() drains each block's
//      outstanding ops before thread0 bumps the counter. Round 3->4 lesson:
//      each threadfence (wbl2+inv) cost ~26 us; this kernel now has ZERO. ----
__device__ __forceinline__ void gbar(unsigned* bar){
  __syncthreads();
  if (threadIdx.x == 0){
    __hip_atomic_fetch_add(bar, 1u, __ATOMIC_RELAXED, __HIP_MEMORY_SCOPE_AGENT);
    unsigned spins = 0;
    while (__hip_atomic_load(bar, __ATOMIC_RELAXED, __HIP_MEMORY_SCOPE_AGENT) < NBLK){
      if (++spins > (1u << 20)) break;        // safety valve: fail loud, not hung
      __builtin_amdgcn_s_sleep(8);
    }
  }
  __syncthreads();
}

// ---- 6-stage Stockham radix-4 FFT over 4096 pts in LDS.
//      Result lands in src0 (6 = even number of ping-pongs).
//      sgn=+1 forward, -1 inverse. Caller must __syncthreads() after filling src0.
__device__ __forceinline__ void fft_r4(float2* src0, float2* dst0,
                                       const float2* __restrict__ tw, float sgn){
  float2* src = src0; float2* dst = dst0;
  const int tid = threadIdx.x;
  #pragma unroll
  for (int st = 0; st < 6; ++st){
    const int sh = 2 * st;
    const int L = 1 << sh;
    const int Lmask = L - 1;
    #pragma unroll
    for (int bf = 0; bf < 4; ++bf){
      int idx = tid + (bf << 8);            // 0..1023
      int q  = idx & Lmask;
      int tb = idx ^ q;                     // p*L  (<= 1023)
      float2 a = src[idx];
      float2 b = src[idx + 1024];
      float2 c = src[idx + 2048];
      float2 d = src[idx + 3072];
      float2 w1 = tw[tb];
      float2 w2 = tw[2 * tb];
      float2 w3 = tw[3 * tb];
      float w1y = sgn * w1.y, w2y = sgn * w2.y, w3y = sgn * w3.y;
      float t0x = a.x + c.x, t0y = a.y + c.y;
      float t1x = a.x - c.x, t1y = a.y - c.y;
      float t2x = b.x + d.x, t2y = b.y + d.y;
      // fwd: -i*(b-d) = (y,-x); inv: +i*(b-d) = (-y,x)
      float t3x = sgn * (b.y - d.y);
      float t3y = -sgn * (b.x - d.x);
      float y0x = t0x + t2x, y0y = t0y + t2y;
      float y1x = t1x + t3x, y1y = t1y + t3y;
      float y2x = t0x - t2x, y2y = t0y - t2y;
      float y3x = t1x - t3x, y3y = t1y - t3y;
      int ob = q + (tb << 2);               // q + 4*p*L
      dst[ob]         = make_float2(y0x, y0y);
      dst[ob + L]     = make_float2(y1x * w1.x - y1y * w1y, y1x * w1y + y1y * w1.x);
      dst[ob + 2 * L] = make_float2(y2x * w2.x - y2y * w2y, y2x * w2y + y2y * w2.x);
      dst[ob + 3 * L] = make_float2(y3x * w3.x - y3y * w3y, y3x * w3y + y3y * w3.x);
    }
    __syncthreads();
    float2* t = src; src = dst; dst = t;
  }
}

// ---- wave-64 shuffle sum ----
__device__ __forceinline__ double wred(double v){
  #pragma unroll
  for (int off = 32; off; off >>= 1) v += __shfl_down(v, off);
  return v;
}

// ---- reduce 9 named doubles (by value) -> atomicAdd (agent scope) into accs ----
__device__ __forceinline__ void red9(double a0, double a1, double a2, double a3,
                                     double a4, double a5, double a6, double a7,
                                     double a8, double* red, double* accs){
  const int tid = threadIdx.x, wave = tid >> 6, lane = tid & 63;
  double r;
  r = wred(a0); if (lane == 0) red[ 0 + wave] = r;
  r = wred(a1); if (lane == 0) red[ 4 + wave] = r;
  r = wred(a2); if (lane == 0) red[ 8 + wave] = r;
  r = wred(a3); if (lane == 0) red[12 + wave] = r;
  r = wred(a4); if (lane == 0) red[16 + wave] = r;
  r = wred(a5); if (lane == 0) red[20 + wave] = r;
  r = wred(a6); if (lane == 0) red[24 + wave] = r;
  r = wred(a7); if (lane == 0) red[28 + wave] = r;
  r = wred(a8); if (lane == 0) red[32 + wave] = r;
  __syncthreads();
  if (tid < 9)
    atomicAdd(&accs[tid], red[tid*4+0] + red[tid*4+1] + red[tid*4+2] + red[tid*4+3]);
}

// ---- per-thread state is NAMED variables only (r4/r5 discipline kept) ----
#define MODE_S(UXc, UYc, OMc, AFP, AP) {                       \
  float ox_ = sx - (UXc), oy_ = sy - (UYc);                    \
  float d_  = fj - (OMc);                                      \
  float den_ = 1.0f + 2000.0f * d_ * d_;                       \
  float nx_ = (Fx - ox_) / den_, ny_ = (Fy - oy_) / den_;      \
  float pw_ = nx_ * nx_ + ny_ * ny_;                           \
  AFP += (double)(fj * pw_);  AP += (double)pw_;               \
  float ddx_ = nx_ - (UXc), ddy_ = ny_ - (UYc);                \
  aD += (double)(ddx_ * ddx_ + ddy_ * ddy_);                   \
  (UXc) = nx_; (UYc) = ny_;                                    \
  sx = ox_ + nx_; sy = oy_ + ny_; }

#define BIN_S(PP, UX, UY) {                                    \
  int j = tid + ((PP) << 8);                                   \
  float2 Fv = bufA[j];                                         \
  float Fx = Fv.x, Fy = Fv.y;                                  \
  float fj = (float)j * (1.0f / 4096.0f);                      \
  float sx = UX.x + UX.y + UX.z + UX.w;                        \
  float sy = UY.x + UY.y + UY.z + UY.w;                        \
  MODE_S(UX.x, UY.x, om.x, aFP0, aP0)                          \
  MODE_S(UX.y, UY.y, om.y, aFP1, aP1)                          \
  MODE_S(UX.z, UY.z, om.z, aFP2, aP2)                          \
  MODE_S(UX.w, UY.w, om.w, aFP3, aP3) }

#define IT1(PP, UX, UY) { UX = make_float4(0.f,0.f,0.f,0.f);   \
                          UY = make_float4(0.f,0.f,0.f,0.f);   \
                          BIN_S(PP, UX, UY) }

#define HERM(PP, UX, UY) {                                     \
  int j = tid + ((PP) << 8);                                   \
  float vx, vy;                                                \
  if (act){                                                    \
    float2 Fv = bufA[j];                                       \
    float sx = UX.y + UX.z + UX.w;                             \
    float sy = UY.y + UY.z + UY.w;                             \
    float fj = (float)j * (1.0f / 4096.0f);                    \
    float dd = fj - om0;                                       \
    float den = 1.0f + 2000.0f * dd * dd;                      \
    vx = (Fv.x - sx) / den; vy = (Fv.y - sy) / den;            \
  } else { vx = UX.x; vy = UY.x; }                             \
  if (j == 0){ bufB[0] = make_float2(vx, -vy); }               \
  else { bufB[j]      = make_float2(vx, vy);                   \
         bufB[T2 - j] = make_float2(vx, -vy); }                \
  if (j == H2 - 1) bufB[H2] = make_float2(vx, -vy); }

#define FOR8(M) M(0,ux0,uy0) M(1,ux1,uy1) M(2,ux2,uy2) M(3,ux3,uy3) \
                M(4,ux4,uy4) M(5,ux5,uy5) M(6,ux6,uy6) M(7,ux7,uy7)

// ---- twiddle table (separate warm-up kernel: kernel boundary = free coherence,
//      so the main kernel needs no fence to see it) ----
__global__ void k_tw(float2* __restrict__ tw){
  int p = blockIdx.x * 256 + threadIdx.x;    // 0..3071
  double a = -6.283185307179586 * (double)p / 4096.0;
  tw[p] = make_float2((float)cos(a), (float)sin(a));
}

// ==== whole pipeline, NO transposes, NO fences, 4 counter barriers ====
// Round-5 lesson: the transposes' only purpose was coalescing, and they forced
// the two remaining ~26us threadfences. Block (b,ch) reads/writes its channel
// directly (stride-256B). blk = b + 8*ch puts all 64 channels of batch b on one
// XCD (blockIdx%8 round-robin heuristic): the 16 sibling channels sharing each
// 64B line read it from one L2 and their partial output writes merge to full
// lines in that L2. Heuristic only — correctness never depends on it (LLC backs).
__global__ void __attribute__((amdgpu_flat_work_group_size(256, 256),
                               amdgpu_waves_per_eu(2, 2)))
k_main(const float* __restrict__ x, const float2* __restrict__ tw,
       unsigned* __restrict__ bar, double* __restrict__ accs,
       float* __restrict__ xh, float* __restrict__ xl){
  __shared__ float2 bufA[T2];
  __shared__ float2 bufB[T2];
  const int blk = blockIdx.x, tid = threadIdx.x;
  const int b = blk & 7, ch = blk >> 3;
  const float* xc = x + (size_t)b * TLEN * 64 + ch;   // this block's channel row

  // ---- mirror-extend + forward FFT; spectrum stays in bufA[0..2047] ----
  #pragma unroll
  for (int pp = 0; pp < 16; ++pp){
    int i = tid + (pp << 8);
    int s = (i < 1024) ? (1023 - i) : ((i < 3072) ? (i - 1024) : (5119 - i));
    bufA[i] = make_float2(xc[(size_t)s * 64], 0.0f);
  }
  __syncthreads();
  fft_r4(bufA, bufB, tw, 1.0f);              // result in bufA; F = bufA[0..2047]

  float4 ux0, ux1, ux2, ux3, ux4, ux5, ux6, ux7;
  float4 uy0, uy1, uy2, uy3, uy4, uy5, uy6, uy7;
  float4 om = make_float4(0.0f, 0.125f, 0.25f, 0.375f);

  // iter 1 (u starts at 0)
  {
    double aFP0=0,aFP1=0,aFP2=0,aFP3=0,aP0=0,aP1=0,aP2=0,aP3=0,aD=0;
    FOR8(IT1)
    red9(aFP0,aFP1,aFP2,aFP3,aP0,aP1,aP2,aP3,aD, (double*)bufB, accs);
  }
  gbar(bar + 0);

  // ---- iters 2..4, u stays in registers, F stays in bufA ----
  bool active = true;
  double* slot = accs;                       // stats of last completed iter
  #pragma unroll 1
  for (int it = 0; it < 3; ++it){
    if (active){
      if (ld_acc(slot + 8) * (1.0 / 4096.0) + EPS32 > 5e-5){
        om.x = (float)(ld_acc(slot + 0) / ld_acc(slot + 4));
        om.y = (float)(ld_acc(slot + 1) / ld_acc(slot + 5));
        om.z = (float)(ld_acc(slot + 2) / ld_acc(slot + 6));
        om.w = (float)(ld_acc(slot + 3) / ld_acc(slot + 7));
      } else active = false;
    }
    if (active){
      double aFP0=0,aFP1=0,aFP2=0,aFP3=0,aP0=0,aP1=0,aP2=0,aP3=0,aD=0;
      FOR8(BIN_S)
      red9(aFP0,aFP1,aFP2,aFP3,aP0,aP1,aP2,aP3,aD, (double*)bufB, slot + 9);
    }
    gbar(bar + 1 + it);
    slot += 9;
  }

  // ---- guarded iter-5 mode-0 update + Hermitian build into bufB,
  //      inverse FFT with (bufB, bufA) -> result lands in bufB ----
  {
    bool act = active;
    float om0 = 0.0f;
    if (act){
      if (ld_acc(slot + 8) * (1.0 / 4096.0) + EPS32 > 5e-5)
        om0 = (float)(ld_acc(slot) / ld_acc(slot + 4));
      else act = false;
    }
    FOR8(HERM)
    __syncthreads();
    fft_r4(bufB, bufA, tw, -1.0f);                    // result in bufB
    const float scale = 1.0f / (float)T2;
    #pragma unroll
    for (int pp = 0; pp < 8; ++pp){
      int t = tid + (pp << 8);
      float xlv = bufB[1024 + t].x * scale;
      size_t oi = ((size_t)(b * TLEN + t)) * 64 + ch;
      float xv = xc[(size_t)t * 64];
      xh[oi] = xv - xlv;
      xl[oi] = xlv;
    }
  }
}

extern "C" void kernel_launch(void* const* d_in, const int* in_sizes, int n_in,
                              void* d_out, int out_size, void* d_ws, size_t ws_size,
                              hipStream_t stream){
  const float* x = (const float*)d_in[0];
  float* out_xh = (float*)d_out;
  float* out_xl = out_xh + (size_t)8 * TLEN * 64;

  char* ws = (char*)d_ws;
  float2* tw   = (float2*)ws;                     // 24 KiB (3072 twiddles)
  char*   sync = ws + 32768;                      // barrier counters + accs
  unsigned* bar  = (unsigned*)sync;               // 16 counters (64 B)
  double*   accs = (double*)(sync + 128);         // 36 doubles

  hipMemsetAsync(sync, 0, 512, stream);           // zero bars + accs
  k_tw<<<12, 256, 0, stream>>>(tw);
  k_main<<<NBLK, 256, 0, stream>>>(x, tw, bar, accs, out_xh, out_xl);
}

// Round 7
// 155.107 us; speedup vs baseline: 2.5521x; 1.1597x over previous
//
#include <hip/hip_runtime.h>
#include <math.h>

#define TLEN 2048
#define T2   4096
#define H2   2048
#define NBLK 512
#define EPS32 1.1920928955078125e-07

// agent-scope atomic load: always reads the coherent copy
__device__ __forceinline__ double ld_acc(const double* p){
  return __hip_atomic_load(p, __ATOMIC_RELAXED, __HIP_MEMORY_SCOPE_AGENT);
}

// ---- pure counter grid barrier (512 co-resident blocks; distinct counter per
//      use, zeroed host-side). NO threadfence: the only cross-block data is accs,
//      written by agent-scope atomicAdd (coherent point) and read via agent-scope
//      atomic loads. Each threadfence cost ~26 us (r3->r4); zero remain. ----
__device__ __forceinline__ void gbar(unsigned* bar){
  __syncthreads();
  if (threadIdx.x == 0){
    __hip_atomic_fetch_add(bar, 1u, __ATOMIC_RELAXED, __HIP_MEMORY_SCOPE_AGENT);
    unsigned spins = 0;
    while (__hip_atomic_load(bar, __ATOMIC_RELAXED, __HIP_MEMORY_SCOPE_AGENT) < NBLK){
      if (++spins > (1u << 20)) break;        // safety valve: fail loud, not hung
      __builtin_amdgcn_s_sleep(8);
    }
  }
  __syncthreads();
}

// ---- 6-stage Stockham radix-4 FFT over 4096 pts in LDS.
//      Result lands in src0 (6 = even number of ping-pongs).
//      sgn=+1 forward, -1 inverse. Caller must __syncthreads() after filling src0.
//      r6 lesson: `#pragma unroll` on the stage loop produced 24 straight-line
//      butterflies whose hoisted addresses/loads blew past the VGPR budget ->
//      ~45 MB of scratch spill writebacks per launch (WRITE_SIZE constant ~58 MB
//      across 4 structurally different kernels). unroll 1 bounds the pressure;
//      the 4-butterfly inner unroll keeps 16 ds_reads + 12 tw loads in flight.
__device__ __forceinline__ void fft_r4(float2* src0, float2* dst0,
                                       const float2* __restrict__ tw, float sgn){
  float2* src = src0; float2* dst = dst0;
  const int tid = threadIdx.x;
  #pragma unroll 1
  for (int st = 0; st < 6; ++st){
    const int sh = 2 * st;
    const int L = 1 << sh;
    const int Lmask = L - 1;
    #pragma unroll
    for (int bf = 0; bf < 4; ++bf){
      int idx = tid + (bf << 8);            // 0..1023
      int q  = idx & Lmask;
      int tb = idx ^ q;                     // p*L  (<= 1023)
      float2 a = src[idx];
      float2 b = src[idx + 1024];
      float2 c = src[idx + 2048];
      float2 d = src[idx + 3072];
      float2 w1 = tw[tb];
      float2 w2 = tw[2 * tb];
      float2 w3 = tw[3 * tb];
      float w1y = sgn * w1.y, w2y = sgn * w2.y, w3y = sgn * w3.y;
      float t0x = a.x + c.x, t0y = a.y + c.y;
      float t1x = a.x - c.x, t1y = a.y - c.y;
      float t2x = b.x + d.x, t2y = b.y + d.y;
      // fwd: -i*(b-d) = (y,-x); inv: +i*(b-d) = (-y,x)
      float t3x = sgn * (b.y - d.y);
      float t3y = -sgn * (b.x - d.x);
      float y0x = t0x + t2x, y0y = t0y + t2y;
      float y1x = t1x + t3x, y1y = t1y + t3y;
      float y2x = t0x - t2x, y2y = t0y - t2y;
      float y3x = t1x - t3x, y3y = t1y - t3y;
      int ob = q + (tb << 2);               // q + 4*p*L
      dst[ob]         = make_float2(y0x, y0y);
      dst[ob + L]     = make_float2(y1x * w1.x - y1y * w1y, y1x * w1y + y1y * w1.x);
      dst[ob + 2 * L] = make_float2(y2x * w2.x - y2y * w2y, y2x * w2y + y2y * w2.x);
      dst[ob + 3 * L] = make_float2(y3x * w3.x - y3y * w3y, y3x * w3y + y3y * w3.x);
    }
    __syncthreads();
    float2* t = src; src = dst; dst = t;
  }
}

// ---- wave-64 shuffle sum ----
__device__ __forceinline__ double wred(double v){
  #pragma unroll
  for (int off = 32; off; off >>= 1) v += __shfl_down(v, off);
  return v;
}

// ---- reduce 9 named doubles (by value) -> atomicAdd (agent scope) into accs ----
__device__ __forceinline__ void red9(double a0, double a1, double a2, double a3,
                                     double a4, double a5, double a6, double a7,
                                     double a8, double* red, double* accs){
  const int tid = threadIdx.x, wave = tid >> 6, lane = tid & 63;
  double r;
  r = wred(a0); if (lane == 0) red[ 0 + wave] = r;
  r = wred(a1); if (lane == 0) red[ 4 + wave] = r;
  r = wred(a2); if (lane == 0) red[ 8 + wave] = r;
  r = wred(a3); if (lane == 0) red[12 + wave] = r;
  r = wred(a4); if (lane == 0) red[16 + wave] = r;
  r = wred(a5); if (lane == 0) red[20 + wave] = r;
  r = wred(a6); if (lane == 0) red[24 + wave] = r;
  r = wred(a7); if (lane == 0) red[28 + wave] = r;
  r = wred(a8); if (lane == 0) red[32 + wave] = r;
  __syncthreads();
  if (tid < 9)
    atomicAdd(&accs[tid], red[tid*4+0] + red[tid*4+1] + red[tid*4+2] + red[tid*4+3]);
}

// ---- per-thread state is NAMED variables only ----
#define MODE_S(UXc, UYc, OMc, AFP, AP) {                       \
  float ox_ = sx - (UXc), oy_ = sy - (UYc);                    \
  float d_  = fj - (OMc);                                      \
  float den_ = 1.0f + 2000.0f * d_ * d_;                       \
  float nx_ = (Fx - ox_) / den_, ny_ = (Fy - oy_) / den_;      \
  float pw_ = nx_ * nx_ + ny_ * ny_;                           \
  AFP += (double)(fj * pw_);  AP += (double)pw_;               \
  float ddx_ = nx_ - (UXc), ddy_ = ny_ - (UYc);                \
  aD += (double)(ddx_ * ddx_ + ddy_ * ddy_);                   \
  (UXc) = nx_; (UYc) = ny_;                                    \
  sx = ox_ + nx_; sy = oy_ + ny_; }

#define BIN_S(PP, UX, UY) {                                    \
  int j = tid + ((PP) << 8);                                   \
  float2 Fv = bufA[j];                                         \
  float Fx = Fv.x, Fy = Fv.y;                                  \
  float fj = (float)j * (1.0f / 4096.0f);                      \
  float sx = UX.x + UX.y + UX.z + UX.w;                        \
  float sy = UY.x + UY.y + UY.z + UY.w;                        \
  MODE_S(UX.x, UY.x, om.x, aFP0, aP0)                          \
  MODE_S(UX.y, UY.y, om.y, aFP1, aP1)                          \
  MODE_S(UX.z, UY.z, om.z, aFP2, aP2)                          \
  MODE_S(UX.w, UY.w, om.w, aFP3, aP3) }

#define IT1(PP, UX, UY) { UX = make_float4(0.f,0.f,0.f,0.f);   \
                          UY = make_float4(0.f,0.f,0.f,0.f);   \
                          BIN_S(PP, UX, UY) }

#define HERM(PP, UX, UY) {                                     \
  int j = tid + ((PP) << 8);                                   \
  float vx, vy;                                                \
  if (act){                                                    \
    float2 Fv = bufA[j];                                       \
    float sx = UX.y + UX.z + UX.w;                             \
    float sy = UY.y + UY.z + UY.w;                             \
    float fj = (float)j * (1.0f / 4096.0f);                    \
    float dd = fj - om0;                                       \
    float den = 1.0f + 2000.0f * dd * dd;                      \
    vx = (Fv.x - sx) / den; vy = (Fv.y - sy) / den;            \
  } else { vx = UX.x; vy = UY.x; }                             \
  if (j == 0){ bufB[0] = make_float2(vx, -vy); }               \
  else { bufB[j]      = make_float2(vx, vy);                   \
         bufB[T2 - j] = make_float2(vx, -vy); }                \
  if (j == H2 - 1) bufB[H2] = make_float2(vx, -vy); }

#define FOR8(M) M(0,ux0,uy0) M(1,ux1,uy1) M(2,ux2,uy2) M(3,ux3,uy3) \
                M(4,ux4,uy4) M(5,ux5,uy5) M(6,ux6,uy6) M(7,ux7,uy7)

// ---- twiddle table (separate warm-up kernel: boundary = free coherence) ----
__global__ void k_tw(float2* __restrict__ tw){
  int p = blockIdx.x * 256 + threadIdx.x;    // 0..3071
  double a = -6.283185307179586 * (double)p / 4096.0;
  tw[p] = make_float2((float)cos(a), (float)sin(a));
}

// ==== whole pipeline, no transposes, no fences, 4 counter barriers ====
// Block (b,ch) reads/writes its channel directly (stride-256B; the 16 channel-
// sibling blocks sharing each 64B line merge in cache). x is read ONCE: the
// middle 8 mirror-extend loads (i=t+1024 => s=t) ARE the epilogue's x values —
// stashed in 8 named floats instead of a second scatter-read pass.
__global__ void __attribute__((amdgpu_flat_work_group_size(256, 256),
                               amdgpu_waves_per_eu(2, 2)))
k_main(const float* __restrict__ x, const float2* __restrict__ tw,
       unsigned* __restrict__ bar, double* __restrict__ accs,
       float* __restrict__ xh, float* __restrict__ xl){
  __shared__ float2 bufA[T2];
  __shared__ float2 bufB[T2];
  const int blk = blockIdx.x, tid = threadIdx.x;
  const int b = blk & 7, ch = blk >> 3;
  const float* xc = x + (size_t)b * TLEN * 64 + ch;   // this block's channel row

  // ---- mirror-extend (single x pass) + forward FFT; F stays in bufA[0..2047] ----
  float xv0, xv1, xv2, xv3, xv4, xv5, xv6, xv7;
  {
    #define MLOADR(PPM) {                                        \
      int i = tid + ((PPM) << 8);                                \
      int s = ((PPM) < 4) ? (1023 - i) : (5119 - i);             \
      bufA[i] = make_float2(xc[(size_t)s * 64], 0.0f); }
    #define MLOADX(PPM, XV) {                                    \
      int i = tid + ((PPM) << 8);                                \
      XV = xc[(size_t)(i - 1024) * 64];                          \
      bufA[i] = make_float2(XV, 0.0f); }
    MLOADR(0) MLOADR(1) MLOADR(2) MLOADR(3)
    MLOADX(4,  xv0) MLOADX(5,  xv1) MLOADX(6,  xv2) MLOADX(7,  xv3)
    MLOADX(8,  xv4) MLOADX(9,  xv5) MLOADX(10, xv6) MLOADX(11, xv7)
    MLOADR(12) MLOADR(13) MLOADR(14) MLOADR(15)
  }
  __syncthreads();
  fft_r4(bufA, bufB, tw, 1.0f);              // result in bufA; F = bufA[0..2047]

  float4 ux0, ux1, ux2, ux3, ux4, ux5, ux6, ux7;
  float4 uy0, uy1, uy2, uy3, uy4, uy5, uy6, uy7;
  float4 om = make_float4(0.0f, 0.125f, 0.25f, 0.375f);

  // iter 1 (u starts at 0)
  {
    double aFP0=0,aFP1=0,aFP2=0,aFP3=0,aP0=0,aP1=0,aP2=0,aP3=0,aD=0;
    FOR8(IT1)
    red9(aFP0,aFP1,aFP2,aFP3,aP0,aP1,aP2,aP3,aD, (double*)bufB, accs);
  }
  gbar(bar + 0);

  // ---- iters 2..4, u stays in registers, F stays in bufA ----
  bool active = true;
  double* slot = accs;                       // stats of last completed iter
  #pragma unroll 1
  for (int it = 0; it < 3; ++it){
    if (active){
      if (ld_acc(slot + 8) * (1.0 / 4096.0) + EPS32 > 5e-5){
        om.x = (float)(ld_acc(slot + 0) / ld_acc(slot + 4));
        om.y = (float)(ld_acc(slot + 1) / ld_acc(slot + 5));
        om.z = (float)(ld_acc(slot + 2) / ld_acc(slot + 6));
        om.w = (float)(ld_acc(slot + 3) / ld_acc(slot + 7));
      } else active = false;
    }
    if (active){
      double aFP0=0,aFP1=0,aFP2=0,aFP3=0,aP0=0,aP1=0,aP2=0,aP3=0,aD=0;
      FOR8(BIN_S)
      red9(aFP0,aFP1,aFP2,aFP3,aP0,aP1,aP2,aP3,aD, (double*)bufB, slot + 9);
    }
    gbar(bar + 1 + it);
    slot += 9;
  }

  // ---- guarded iter-5 mode-0 update + Hermitian build into bufB,
  //      inverse FFT with (bufB, bufA) -> result lands in bufB ----
  {
    bool act = active;
    float om0 = 0.0f;
    if (act){
      if (ld_acc(slot + 8) * (1.0 / 4096.0) + EPS32 > 5e-5)
        om0 = (float)(ld_acc(slot) / ld_acc(slot + 4));
      else act = false;
    }
    FOR8(HERM)
    __syncthreads();
    fft_r4(bufB, bufA, tw, -1.0f);                    // result in bufB
    const float scale = 1.0f / (float)T2;
    #define STOUT(PP, XV) {                                      \
      int t = tid + ((PP) << 8);                                 \
      float xlv = bufB[1024 + t].x * scale;                      \
      size_t oi = ((size_t)(b * TLEN + t)) * 64 + ch;            \
      xh[oi] = XV - xlv;                                         \
      xl[oi] = xlv; }
    STOUT(0, xv0) STOUT(1, xv1) STOUT(2, xv2) STOUT(3, xv3)
    STOUT(4, xv4) STOUT(5, xv5) STOUT(6, xv6) STOUT(7, xv7)
  }
}

extern "C" void kernel_launch(void* const* d_in, const int* in_sizes, int n_in,
                              void* d_out, int out_size, void* d_ws, size_t ws_size,
                              hipStream_t stream){
  const float* x = (const float*)d_in[0];
  float* out_xh = (float*)d_out;
  float* out_xl = out_xh + (size_t)8 * TLEN * 64;

  char* ws = (char*)d_ws;
  float2* tw   = (float2*)ws;                     // 24 KiB (3072 twiddles)
  char*   sync = ws + 32768;                      // barrier counters + accs
  unsigned* bar  = (unsigned*)sync;               // 16 counters (64 B)
  double*   accs = (double*)(sync + 128);         // 36 doubles

  hipMemsetAsync(sync, 0, 512, stream);           // zero bars + accs
  k_tw<<<12, 256, 0, stream>>>(tw);
  k_main<<<NBLK, 256, 0, stream>>>(x, tw, bar, accs, out_xh, out_xl);
}

// Round 8
// 142.997 us; speedup vs baseline: 2.7683x; 1.0847x over previous
//
#include <hip/hip_runtime.h>
#include <math.h>

#define TLEN 2048
#define T2   4096
#define H2   2048
#define NBLK 512
#define EPS32 1.1920928955078125e-07

// agent-scope atomic load: always reads the coherent copy
__device__ __forceinline__ double ld_acc(const double* p){
  return __hip_atomic_load(p, __ATOMIC_RELAXED, __HIP_MEMORY_SCOPE_AGENT);
}

// ---- pure counter grid barrier (512 co-resident blocks; distinct counter per
//      use, zeroed host-side). NO threadfence (r4 lesson: ~26us each): the only
//      cross-block data is accs via agent-scope atomics. ----
__device__ __forceinline__ void gbar(unsigned* bar){
  __syncthreads();
  if (threadIdx.x == 0){
    __hip_atomic_fetch_add(bar, 1u, __ATOMIC_RELAXED, __HIP_MEMORY_SCOPE_AGENT);
    unsigned spins = 0;
    while (__hip_atomic_load(bar, __ATOMIC_RELAXED, __HIP_MEMORY_SCOPE_AGENT) < NBLK){
      if (++spins > (1u << 20)) break;        // safety valve: fail loud, not hung
      __builtin_amdgcn_s_sleep(8);
    }
  }
  __syncthreads();
}

// ---- 2048-pt complex FFT in LDS: 1 radix-2 + 5 radix-4 Stockham stages.
//      Result lands in src0 (6 stages = even ping-pong count). sgn=+1 fwd, -1 inv.
//      tw[p] = e^{-2pi i p/4096}: radix-2 uses tw[2p], radix-4 tw[2tb/4tb/6tb]
//      (max index 6*510=3060 < 3072). r6 lesson: stage loop stays `unroll 1`
//      (full unroll -> VGPR blowout -> scratch spills). ----
__device__ __forceinline__ void fft2048(float2* src0, float2* dst0,
                                        const float2* __restrict__ tw, float sgn){
  const int tid = threadIdx.x;
  // radix-2 stage (L=1): dst[2p],dst[2p+1] merged into one float4 store
  #pragma unroll
  for (int bf = 0; bf < 4; ++bf){
    int p = tid + (bf << 8);                  // 0..1023
    float2 a = src0[p], b = src0[p + 1024];
    float2 w = tw[2 * p];
    float wy = sgn * w.y;
    float dx = a.x - b.x, dy = a.y - b.y;
    *reinterpret_cast<float4*>(&dst0[2 * p]) =
      make_float4(a.x + b.x, a.y + b.y, dx * w.x - dy * wy, dx * wy + dy * w.x);
  }
  __syncthreads();
  // 5 radix-4 stages: L = 2,8,32,128,512
  float2* src = dst0; float2* dst = src0;
  #pragma unroll 1
  for (int t = 0; t < 5; ++t){
    const int L = 2 << (2 * t);
    const int Lm = L - 1;
    #pragma unroll
    for (int bf = 0; bf < 2; ++bf){
      int idx = tid + (bf << 8);              // 0..511
      int q  = idx & Lm;
      int tb = idx - q;                       // p*L (<= 510)
      float2 a = src[idx];
      float2 b = src[idx + 512];
      float2 c = src[idx + 1024];
      float2 d = src[idx + 1536];
      float2 w1 = tw[2 * tb];
      float2 w2 = tw[4 * tb];
      float2 w3 = tw[6 * tb];
      float w1y = sgn * w1.y, w2y = sgn * w2.y, w3y = sgn * w3.y;
      float t0x = a.x + c.x, t0y = a.y + c.y;
      float t1x = a.x - c.x, t1y = a.y - c.y;
      float t2x = b.x + d.x, t2y = b.y + d.y;
      // fwd: -i*(b-d) = (y,-x); inv: +i*(b-d) = (-y,x)
      float t3x = sgn * (b.y - d.y);
      float t3y = -sgn * (b.x - d.x);
      float y0x = t0x + t2x, y0y = t0y + t2y;
      float y1x = t1x + t3x, y1y = t1y + t3y;
      float y2x = t0x - t2x, y2y = t0y - t2y;
      float y3x = t1x - t3x, y3y = t1y - t3y;
      int ob = q + (tb << 2);                 // q + 4*p*L
      dst[ob]         = make_float2(y0x, y0y);
      dst[ob + L]     = make_float2(y1x * w1.x - y1y * w1y, y1x * w1y + y1y * w1.x);
      dst[ob + 2 * L] = make_float2(y2x * w2.x - y2y * w2y, y2x * w2y + y2y * w2.x);
      dst[ob + 3 * L] = make_float2(y3x * w3.x - y3y * w3y, y3x * w3y + y3y * w3.x);
    }
    __syncthreads();
    float2* tt = src; src = dst; dst = tt;
  }
}

// ---- wave-64 shuffle sum ----
__device__ __forceinline__ double wred(double v){
  #pragma unroll
  for (int off = 32; off; off >>= 1) v += __shfl_down(v, off);
  return v;
}

// ---- reduce 9 named doubles (by value) -> atomicAdd (agent scope) into accs ----
__device__ __forceinline__ void red9(double a0, double a1, double a2, double a3,
                                     double a4, double a5, double a6, double a7,
                                     double a8, double* red, double* accs){
  const int tid = threadIdx.x, wave = tid >> 6, lane = tid & 63;
  double r;
  r = wred(a0); if (lane == 0) red[ 0 + wave] = r;
  r = wred(a1); if (lane == 0) red[ 4 + wave] = r;
  r = wred(a2); if (lane == 0) red[ 8 + wave] = r;
  r = wred(a3); if (lane == 0) red[12 + wave] = r;
  r = wred(a4); if (lane == 0) red[16 + wave] = r;
  r = wred(a5); if (lane == 0) red[20 + wave] = r;
  r = wred(a6); if (lane == 0) red[24 + wave] = r;
  r = wred(a7); if (lane == 0) red[28 + wave] = r;
  r = wred(a8); if (lane == 0) red[32 + wave] = r;
  __syncthreads();
  if (tid < 9)
    atomicAdd(&accs[tid], red[tid*4+0] + red[tid*4+1] + red[tid*4+2] + red[tid*4+3]);
}

// ---- per-thread state is NAMED variables only; F lives in bufB ----
#define MODE_S(UXc, UYc, OMc, AFP, AP) {                       \
  float ox_ = sx - (UXc), oy_ = sy - (UYc);                    \
  float d_  = fj - (OMc);                                      \
  float den_ = 1.0f + 2000.0f * d_ * d_;                       \
  float nx_ = (Fx - ox_) / den_, ny_ = (Fy - oy_) / den_;      \
  float pw_ = nx_ * nx_ + ny_ * ny_;                           \
  AFP += (double)(fj * pw_);  AP += (double)pw_;               \
  float ddx_ = nx_ - (UXc), ddy_ = ny_ - (UYc);                \
  aD += (double)(ddx_ * ddx_ + ddy_ * ddy_);                   \
  (UXc) = nx_; (UYc) = ny_;                                    \
  sx = ox_ + nx_; sy = oy_ + ny_; }

#define BIN_S(PP, UX, UY) {                                    \
  int j = tid + ((PP) << 8);                                   \
  float2 Fv = bufB[j];                                         \
  float Fx = Fv.x, Fy = Fv.y;                                  \
  float fj = (float)j * (1.0f / 4096.0f);                      \
  float sx = UX.x + UX.y + UX.z + UX.w;                        \
  float sy = UY.x + UY.y + UY.z + UY.w;                        \
  MODE_S(UX.x, UY.x, om.x, aFP0, aP0)                          \
  MODE_S(UX.y, UY.y, om.y, aFP1, aP1)                          \
  MODE_S(UX.z, UY.z, om.z, aFP2, aP2)                          \
  MODE_S(UX.w, UY.w, om.w, aFP3, aP3) }

#define IT1(PP, UX, UY) { UX = make_float4(0.f,0.f,0.f,0.f);   \
                          UY = make_float4(0.f,0.f,0.f,0.f);   \
                          BIN_S(PP, UX, UY) }

// iter-5 mode-0 update; write U[j] (positive-half spectrum) into bufA
#define HERMU(PP, UX, UY) {                                    \
  int j = tid + ((PP) << 8);                                   \
  float vx, vy;                                                \
  if (act){                                                    \
    float2 Fv = bufB[j];                                       \
    float sx = UX.y + UX.z + UX.w;                             \
    float sy = UY.y + UY.z + UY.w;                             \
    float fj = (float)j * (1.0f / 4096.0f);                    \
    float dd = fj - om0;                                       \
    float den = 1.0f + 2000.0f * dd * dd;                      \
    vx = (Fv.x - sx) / den; vy = (Fv.y - sy) / den;            \
  } else { vx = UX.x; vy = UY.x; }                             \
  bufA[j] = make_float2(vx, vy); }

#define FOR8(M) M(0,ux0,uy0) M(1,ux1,uy1) M(2,ux2,uy2) M(3,ux3,uy3) \
                M(4,ux4,uy4) M(5,ux5,uy5) M(6,ux6,uy6) M(7,ux7,uy7)

// ---- twiddle table (separate warm-up kernel: boundary = free coherence) ----
__global__ void k_tw(float2* __restrict__ tw){
  int p = blockIdx.x * 256 + threadIdx.x;    // 0..3071
  double a = -6.283185307179586 * (double)p / 4096.0;
  tw[p] = make_float2((float)cos(a), (float)sin(a));
}

// ==== pipeline with HALF-SIZE (2048-pt) real-packed FFTs ====
// fwd: z[m]=fM[2m]+i*fM[2m+1]; Z=FFT2048(z); F[k]=(Z[k]+conj(Zm))/2
//      - (i/2) tw[k] (Z[k]-conj(Zm)), Zm=Z[(2048-k)&2047]  (verified on N=4 case)
// inv: Hermitian part of reference S has half-spectrum H[0]=Re U0, H[k]=U[k],
//      H[2048]=Re U2047; E'=H[k]+H[k+2048], O'=(H[k]-H[k+2048])conj(tw[k]);
//      z'=IFFT2048(E'+iO'); s[2m]=Re z'/4096, s[2m+1]=Im z'/4096.
__global__ void __attribute__((amdgpu_flat_work_group_size(256, 256),
                               amdgpu_waves_per_eu(2, 2)))
k_main(const float* __restrict__ x, const float2* __restrict__ tw,
       unsigned* __restrict__ bar, double* __restrict__ accs,
       float* __restrict__ xh, float* __restrict__ xl){
  __shared__ float2 bufA[H2];                 // 16 KiB
  __shared__ float2 bufB[H2];                 // 16 KiB
  __shared__ float somf[8];                   // omega/flag broadcast
  const int blk = blockIdx.x, tid = threadIdx.x;
  const int b = blk & 7, ch = blk >> 3;
  const float* xc = x + (size_t)b * TLEN * 64 + ch;

  // ---- pack z[m] = fM[2m] + i*fM[2m+1] (mirror-extend folded in; x read ONCE,
  //      middle values stashed for the epilogue) ----
  float xe0, xe1, xe2, xe3, xo0, xo1, xo2, xo3;
  #pragma unroll
  for (int pp = 0; pp < 2; ++pp){             // n=2m < 1024: s = 1023-n
    int m = tid + (pp << 8);
    bufA[m] = make_float2(xc[(size_t)(1023 - 2*m) * 64],
                          xc[(size_t)(1022 - 2*m) * 64]);
  }
  #define PACKMID(PP, XE, XO) {               /* 1024 <= n < 3072: s = n-1024 */ \
    int m = tid + ((PP) << 8);                                                   \
    int t = 2*m - 1024;                                                          \
    XE = xc[(size_t)t * 64];                                                     \
    XO = xc[(size_t)(t + 1) * 64];                                               \
    bufA[m] = make_float2(XE, XO); }
  PACKMID(2, xe0, xo0)
  PACKMID(3, xe1, xo1)
  PACKMID(4, xe2, xo2)
  PACKMID(5, xe3, xo3)
  #pragma unroll
  for (int pp = 6; pp < 8; ++pp){             // n >= 3072: s = 5119-n
    int m = tid + (pp << 8);
    bufA[m] = make_float2(xc[(size_t)(5119 - 2*m) * 64],
                          xc[(size_t)(5118 - 2*m) * 64]);
  }
  __syncthreads();
  fft2048(bufA, bufB, tw, 1.0f);              // Z in bufA

  // ---- unpack to F[k] (k=0..2047) in bufB ----
  #pragma unroll
  for (int pp = 0; pp < 8; ++pp){
    int k = tid + (pp << 8);
    float2 A  = bufA[k];
    float2 Zm = bufA[(2048 - k) & 2047];
    float px = 0.5f * (A.x + Zm.x), py = 0.5f * (A.y - Zm.y);
    float qx = 0.5f * (A.x - Zm.x), qy = 0.5f * (A.y + Zm.y);
    float2 W = tw[k];
    bufB[k] = make_float2(px + W.x * qy + W.y * qx,
                          py - W.x * qx + W.y * qy);
  }
  __syncthreads();   // all Z reads done before red9 scribbles bufA

  float4 ux0, ux1, ux2, ux3, ux4, ux5, ux6, ux7;
  float4 uy0, uy1, uy2, uy3, uy4, uy5, uy6, uy7;
  float4 om = make_float4(0.0f, 0.125f, 0.25f, 0.375f);

  // iter 1 (u starts at 0)
  {
    double aFP0=0,aFP1=0,aFP2=0,aFP3=0,aP0=0,aP1=0,aP2=0,aP3=0,aD=0;
    FOR8(IT1)
    red9(aFP0,aFP1,aFP2,aFP3,aP0,aP1,aP2,aP3,aD, (double*)bufA, accs);
  }

  // ---- iters 2..4: omega via per-block LDS broadcast (r7 had every THREAD do
  //      9 agent-scope loads to the same line: ~1.2M serialized LLC reads/iter;
  //      now 9 loads per BLOCK) ----
  bool active = true;
  double* slot = accs;
  #pragma unroll 1
  for (int it = 0; it < 3; ++it){
    gbar(bar + it);
    if (tid < 4) somf[tid] = (float)(ld_acc(slot + tid) / ld_acc(slot + 4 + tid));
    if (tid == 7) somf[7] = (ld_acc(slot + 8) * (1.0/4096.0) + EPS32 > 5e-5) ? 1.f : 0.f;
    __syncthreads();
    if (active){
      if (somf[7] != 0.0f){
        om.x = somf[0]; om.y = somf[1]; om.z = somf[2]; om.w = somf[3];
      } else active = false;
    }
    if (active){
      double aFP0=0,aFP1=0,aFP2=0,aFP3=0,aP0=0,aP1=0,aP2=0,aP3=0,aD=0;
      FOR8(BIN_S)
      red9(aFP0,aFP1,aFP2,aFP3,aP0,aP1,aP2,aP3,aD, (double*)bufA, slot + 9);
    }
    slot += 9;
  }
  gbar(bar + 3);

  // ---- guarded iter-5 mode-0 update; U -> bufA; Z' -> bufB; IFFT ----
  if (tid == 0) somf[0] = (float)(ld_acc(slot) / ld_acc(slot + 4));
  if (tid == 7) somf[7] = (ld_acc(slot + 8) * (1.0/4096.0) + EPS32 > 5e-5) ? 1.f : 0.f;
  __syncthreads();
  {
    bool act = active && (somf[7] != 0.0f);
    float om0 = somf[0];
    FOR8(HERMU)                               // reads F (bufB), writes U (bufA)
    __syncthreads();
    #pragma unroll
    for (int pp = 0; pp < 8; ++pp){           // build Z' into bufB
      int k = tid + (pp << 8);
      float2 Zv;
      if (k == 0){
        float e = bufA[0].x + bufA[2047].x;   // Re U0 + Re U2047
        float o = bufA[0].x - bufA[2047].x;
        Zv = make_float2(e, o);
      } else {
        float2 A  = bufA[k];
        float2 Bm = bufA[2048 - k];           // U[2048-k]
        float ex = A.x + Bm.x, ey = A.y - Bm.y;   // A + conj(Bm)
        float dx = A.x - Bm.x, dy = A.y + Bm.y;   // A - conj(Bm)
        float2 W = tw[k];                     // O' = D * conj(W)
        float ox = dx * W.x + dy * W.y;
        float oy = dy * W.x - dx * W.y;
        Zv = make_float2(ex - oy, ey + ox);   // E' + i O'
      }
      bufB[k] = Zv;
    }
    __syncthreads();
    fft2048(bufB, bufA, tw, -1.0f);           // z' in bufB
  }

  // ---- epilogue: s[1024+t] pairs from z'[512..1535]; x from the stash ----
  {
    const float scale = 1.0f / 4096.0f;
    #define STOUT2(MOFF, XE, XO) {                              \
      float2 zv = bufB[512 + tid + (MOFF)];                     \
      int t0 = 2 * tid + ((MOFF) << 1);                         \
      size_t o0 = ((size_t)(b * TLEN + t0)) * 64 + ch;          \
      float l0 = zv.x * scale, l1 = zv.y * scale;               \
      xh[o0]      = XE - l0;  xl[o0]      = l0;                 \
      xh[o0 + 64] = XO - l1;  xl[o0 + 64] = l1; }
    STOUT2(0,   xe0, xo0)
    STOUT2(256, xe1, xo1)
    STOUT2(512, xe2, xo2)
    STOUT2(768, xe3, xo3)
  }
}

extern "C" void kernel_launch(void* const* d_in, const int* in_sizes, int n_in,
                              void* d_out, int out_size, void* d_ws, size_t ws_size,
                              hipStream_t stream){
  const float* x = (const float*)d_in[0];
  float* out_xh = (float*)d_out;
  float* out_xl = out_xh + (size_t)8 * TLEN * 64;

  char* ws = (char*)d_ws;
  float2* tw   = (float2*)ws;                     // 24 KiB (3072 twiddles)
  char*   sync = ws + 32768;                      // barrier counters + accs
  unsigned* bar  = (unsigned*)sync;               // 16 counters (64 B)
  double*   accs = (double*)(sync + 128);         // 36 doubles

  hipMemsetAsync(sync, 0, 512, stream);           // zero bars + accs
  k_tw<<<12, 256, 0, stream>>>(tw);
  k_main<<<NBLK, 256, 0, stream>>>(x, tw, bar, accs, out_xh, out_xl);
}